// Round 5
// baseline (721.745 us; speedup 1.0000x reference)
//
#include <hip/hip_runtime.h>

#define BB 16
#define CIN 32
#define NN 4096
#define TT 12
#define HH 64
#define MM 128
#define DD 64
#define TC (TT*HH)            // 768
#define V1OFF 50331648        // B*H*N*T floats
#define V2OFF 50855936
#define KVELEM (MM*TC)        // 98304 per batch
#define NORMR 0.35355339059327373f   // 64^-0.25
#define RATIO 0.08838834764831845f   // 128^-0.5
#define FEPS 1e-4f

typedef __attribute__((ext_vector_type(8))) short bf16x8;
typedef __attribute__((ext_vector_type(4))) float f32x4;

union BF8 { unsigned short s[8]; bf16x8 v; };

__device__ inline float wave_max(float v) {
#pragma unroll
  for (int off = 32; off > 0; off >>= 1) v = fmaxf(v, __shfl_xor(v, off));
  return v;
}

__device__ inline unsigned short f2bf(float f) {
  unsigned int u = __float_as_uint(f);
  unsigned int r = (u + 0x7FFFu + ((u >> 16) & 1u)) >> 16;
  return (unsigned short)r;
}

// split float into hi/lo bf16 (hi + lo reconstructs to ~2^-17 rel)
__device__ inline void hilo(float v, unsigned short& h, unsigned short& l) {
  h = f2bf(v);
  float fh = __uint_as_float((unsigned int)h << 16);
  l = f2bf(v - fh);
}

// ---- tiny setup kernels -------------------------------------------------

// stack [Wi;Wo] into 128x32 and split hi/lo
__global__ __launch_bounds__(256) void k_wsplit(const float* __restrict__ Wi,
    const float* __restrict__ Wo, unsigned short* __restrict__ whi,
    unsigned short* __restrict__ wlo) {
  int idx = blockIdx.x * 256 + threadIdx.x;   // 4096
  int o = idx >> 5, c = idx & 31;
  float w = (o < 64) ? Wi[o * 32 + c] : Wo[(o - 64) * 32 + c];
  unsigned short h, l; hilo(w, h, l);
  whi[idx] = h; wlo[idx] = l;
}

// K1: per-row features. v1p final (+hi/lo planes); t2 = dash2-diag2 into v2p slot.
__global__ __launch_bounds__(128) void k_feat(const float* __restrict__ nv1,
    const float* __restrict__ nv2, const float* __restrict__ proj,
    float* __restrict__ v1p, float* __restrict__ t2, float* __restrict__ rowmax2,
    unsigned short* __restrict__ v1phi, unsigned short* __restrict__ v1plo) {
  int n = blockIdx.x, m = threadIdx.x;
  __shared__ float a1[DD], a2[DD], r1[2], r2[2];
  if (m < DD) a1[m] = nv1[n * DD + m];
  else        a2[m - DD] = nv2[n * DD + (m - DD)];
  __syncthreads();
  float s1 = 0.f, s2 = 0.f, d1 = 0.f, d2 = 0.f;
  const float* pr = proj + m * DD;
#pragma unroll 8
  for (int d = 0; d < DD; d++) {
    float x1 = a1[d], x2 = a2[d], p = pr[d];
    s1 += x1 * x1; s2 += x2 * x2;
    d1 += x1 * p;  d2 += x2 * p;
  }
  d1 *= NORMR; d2 *= NORMR;
  float diag1 = 0.0625f * s1, diag2 = 0.0625f * s2;
  float mx1 = wave_max(d1), mx2 = wave_max(d2);
  int wv = m >> 6;
  if ((m & 63) == 0) { r1[wv] = mx1; r2[wv] = mx2; }
  __syncthreads();
  mx1 = fmaxf(r1[0], r1[1]); mx2 = fmaxf(r2[0], r2[1]);
  float val = RATIO * (__expf(d1 - diag1 - mx1) + FEPS);
  v1p[n * MM + m] = val;
  unsigned short h, l; hilo(val, h, l);
  v1phi[n * MM + m] = h;
  v1plo[n * MM + m] = l;
  t2[n * MM + m] = d2 - diag2;
  if (m == 0) rowmax2[n] = mx2;
}

// K2: global max of dash2
__global__ __launch_bounds__(256) void k_stab(const float* __restrict__ rowmax2,
                                              float* __restrict__ stab2) {
  int tid = threadIdx.x;
  float mx = -3.4e38f;
  for (int i = tid; i < NN; i += 256) mx = fmaxf(mx, rowmax2[i]);
  mx = wave_max(mx);
  __shared__ float r[4];
  if ((tid & 63) == 0) r[tid >> 6] = mx;
  __syncthreads();
  if (tid == 0) stab2[0] = fmaxf(fmaxf(r[0], r[1]), fmaxf(r[2], r[3]));
}

// K3: finish v2p in place, colsum, and write transposed hi/lo planes [m][n]
__global__ __launch_bounds__(128) void k_v2p(float* __restrict__ t2v2p,
    const float* __restrict__ stab2, float* __restrict__ colsum,
    unsigned short* __restrict__ v2phiT, unsigned short* __restrict__ v2ploT) {
  int m = threadIdx.x;
  float stab = stab2[0];
  float cs = 0.f;
  int n0 = blockIdx.x * 64;   // contiguous chunk for write-combining
  for (int i = 0; i < 64; i++) {
    int n = n0 + i;
    float v = RATIO * (__expf(t2v2p[n * MM + m] - stab) + FEPS);
    t2v2p[n * MM + m] = v;
    cs += v;
    unsigned short h, l; hilo(v, h, l);
    v2phiT[(size_t)m * NN + n] = h;
    v2ploT[(size_t)m * NN + n] = l;
  }
  atomicAdd(&colsum[m], cs);
}

// K4: inv_den[n] = 1 / (v1p[n,:] . colsum)
__global__ __launch_bounds__(256) void k_den(const float* __restrict__ v1p,
    const float* __restrict__ colsum, float* __restrict__ invden) {
  __shared__ float cs[MM];
  int tid = threadIdx.x;
  if (tid < MM) cs[tid] = colsum[tid];
  __syncthreads();
  int n = blockIdx.x * 256 + tid;
  const float* vp = v1p + (size_t)n * MM;
  float s = 0.f;
#pragma unroll 8
  for (int m = 0; m < MM; m++) s += vp[m] * cs[m];
  invden[n] = 1.0f / s;
}

// ---- K5: conv+gate via MFMA. A = stacked W[128x32] hi/lo (regs), B = input.
// x stored hi/lo bf16 planes, layout [b][n/8][j=t*64+h][n%8].
// Stream-once reads: each lane preloads its full 48B t-rows (3x float4)
// for all 8 channels, converts once to per-t bf16 hi/lo packs, then computes
// all 12 t out of registers.
__global__ __launch_bounds__(256) void k_point(const float* __restrict__ inp,
    const unsigned short* __restrict__ whi, const unsigned short* __restrict__ wlo,
    const float* __restrict__ bi, const float* __restrict__ bo,
    unsigned short* __restrict__ xhi, unsigned short* __restrict__ xlo) {
  int tid = threadIdx.x;
  int wv = tid >> 6, lane = tid & 63;
  int quad = lane >> 4, l16 = lane & 15;
  int b = blockIdx.y;
  int n = blockIdx.x * 64 + wv * 16 + l16;

  bf16x8 wh[8], wl[8];
#pragma unroll
  for (int tile = 0; tile < 8; tile++) {
    int m = tile * 16 + l16;
    wh[tile] = *(const bf16x8*)(whi + m * 32 + quad * 8);
    wl[tile] = *(const bf16x8*)(wlo + m * 32 + quad * 8);
  }
  f32x4 binit[8];
#pragma unroll
  for (int tile = 0; tile < 8; tile++) {
    const float* bp = (tile < 4) ? bi : bo;
#pragma unroll
    for (int r = 0; r < 4; r++)
      binit[tile][r] = bp[(tile & 3) * 16 + quad * 4 + r];
  }
  const float* ipb = inp + ((size_t)b * CIN + quad * 8) * (NN * TT) + (size_t)n * TT;

  // preload all 12 t for the 8 channels of this quad; convert once.
  BF8 xh[TT], xl[TT];
#pragma unroll
  for (int j = 0; j < 8; j++) {
    const float* rp = ipb + (size_t)j * (NN * TT);
    float4 r0 = *(const float4*)(rp + 0);
    float4 r1 = *(const float4*)(rp + 4);
    float4 r2 = *(const float4*)(rp + 8);
    float row[TT] = {r0.x, r0.y, r0.z, r0.w, r1.x, r1.y, r1.z, r1.w,
                     r2.x, r2.y, r2.z, r2.w};
#pragma unroll
    for (int t = 0; t < TT; t++) {
      unsigned short h, l; hilo(row[t], h, l);
      xh[t].s[j] = h; xl[t].s[j] = l;
    }
  }

  size_t xbase = ((size_t)(b * (NN / 8) + (n >> 3)) * TC) * 8 + (n & 7);
#pragma unroll
  for (int t = 0; t < TT; t++) {
    f32x4 acc[8];
#pragma unroll
    for (int tile = 0; tile < 8; tile++) acc[tile] = binit[tile];
#pragma unroll
    for (int tile = 0; tile < 8; tile++) {
      acc[tile] = __builtin_amdgcn_mfma_f32_16x16x32_bf16(wh[tile], xh[t].v, acc[tile], 0, 0, 0);
      acc[tile] = __builtin_amdgcn_mfma_f32_16x16x32_bf16(wh[tile], xl[t].v, acc[tile], 0, 0, 0);
      acc[tile] = __builtin_amdgcn_mfma_f32_16x16x32_bf16(wl[tile], xh[t].v, acc[tile], 0, 0, 0);
    }
#pragma unroll
    for (int i = 0; i < 4; i++) {
#pragma unroll
      for (int r = 0; r < 4; r++) {
        float h1 = acc[i][r], h2 = acc[i + 4][r];
        float g = h2 / (1.f + __expf(-h1));
        unsigned short gh, gl; hilo(g, gh, gl);
        int j = t * 64 + i * 16 + quad * 4 + r;
        xhi[xbase + (size_t)j * 8] = gh;
        xlo[xbase + (size_t)j * 8] = gl;
      }
    }
  }
}

// ---- K6: kv partials via MFMA. A = v2pT hi/lo, B = x hi/lo.
// grid (12 jt, NS, 16 b); wave handles all 8 m-tiles x 16 j (1 j-frag).
// Halved per-wave j-tile vs round-4 (was 2 j-frags, acc 64 VGPR, 768
// blocks, 16% occ, latency-bound): acc->32 VGPR, 1536 blocks. Formulas
// are the jf=0 specialization of the passing round-4 code.
__global__ __launch_bounds__(256) void k_kv(const unsigned short* __restrict__ xhi,
    const unsigned short* __restrict__ xlo,
    const unsigned short* __restrict__ v2phiT, const unsigned short* __restrict__ v2ploT,
    float* __restrict__ kvpart) {
  int tid = threadIdx.x, wv = tid >> 6, lane = tid & 63;
  int quad = lane >> 4, l16 = lane & 15;
  int jt = blockIdx.x, nsI = blockIdx.y, b = blockIdx.z;
  int NS = gridDim.y, kPer = NN / NS;
  int j0 = jt * 64 + wv * 16;
  f32x4 zz = {0.f, 0.f, 0.f, 0.f};
  f32x4 acc[8];
#pragma unroll
  for (int t = 0; t < 8; t++) acc[t] = zz;
  int kend = nsI * kPer + kPer;
  for (int k0 = nsI * kPer; k0 < kend; k0 += 32) {
    bf16x8 ah[8], al[8];
#pragma unroll
    for (int tile = 0; tile < 8; tile++) {
      size_t off = (size_t)(tile * 16 + l16) * NN + k0 + quad * 8;
      ah[tile] = *(const bf16x8*)(v2phiT + off);
      al[tile] = *(const bf16x8*)(v2ploT + off);
    }
    bf16x8 bh, bl;
    {
      size_t off = ((size_t)(b * (NN / 8) + (k0 >> 3) + quad) * TC + j0 + l16) * 8;
      bh = *(const bf16x8*)(xhi + off);
      bl = *(const bf16x8*)(xlo + off);
    }
#pragma unroll
    for (int tile = 0; tile < 8; tile++) {
      acc[tile] = __builtin_amdgcn_mfma_f32_16x16x32_bf16(ah[tile], bh, acc[tile], 0, 0, 0);
      acc[tile] = __builtin_amdgcn_mfma_f32_16x16x32_bf16(ah[tile], bl, acc[tile], 0, 0, 0);
      acc[tile] = __builtin_amdgcn_mfma_f32_16x16x32_bf16(al[tile], bh, acc[tile], 0, 0, 0);
    }
  }
  float* dst = kvpart + (size_t)(nsI * BB + b) * KVELEM;
#pragma unroll
  for (int tile = 0; tile < 8; tile++)
#pragma unroll
    for (int r = 0; r < 4; r++)
      dst[(size_t)(tile * 16 + quad * 4 + r) * TC + j0 + l16] = acc[tile][r];
}

// K6b: reduce NS partials, emit kvB hi/lo planes [b][m/8][j][m%8]
__global__ __launch_bounds__(256) void k_kvred(const float* __restrict__ kvpart,
    unsigned short* __restrict__ kvBhi, unsigned short* __restrict__ kvBlo, int NS) {
  int gid = blockIdx.x * 256 + threadIdx.x;   // 196608
  int j = gid % TC; int rest = gid / TC; int mgrp = rest & 15; int b = rest >> 4;
  float s[8];
#pragma unroll
  for (int mi = 0; mi < 8; mi++) s[mi] = 0.f;
  for (int ns = 0; ns < NS; ns++) {
    const float* p = kvpart + ((size_t)(ns * BB + b) * MM + mgrp * 8) * TC + j;
#pragma unroll
    for (int mi = 0; mi < 8; mi++) s[mi] += p[(size_t)mi * TC];
  }
  unsigned short hs[8] __attribute__((aligned(16)));
  unsigned short ls[8] __attribute__((aligned(16)));
#pragma unroll
  for (int mi = 0; mi < 8; mi++) hilo(s[mi], hs[mi], ls[mi]);
  size_t off = ((size_t)(b * 16 + mgrp) * TC + j) * 8;
  *(uint4*)(kvBhi + off) = *(const uint4*)hs;
  *(uint4*)(kvBlo + off) = *(const uint4*)ls;
}

// ---- K7: num = v1p . kv via MFMA, scale by invden, write [B,H,N,T].
// grid (256 nt, 16 b); wave: 16 n x 16 h x all 12 t. (n-split version;
// t-split variant failed correctness twice — quarantined.)
__global__ __launch_bounds__(256) void k_num(const unsigned short* __restrict__ v1phi,
    const unsigned short* __restrict__ v1plo, const unsigned short* __restrict__ kvBhi,
    const unsigned short* __restrict__ kvBlo, const float* __restrict__ invden,
    float* __restrict__ out) {
  int tid = threadIdx.x, wv = tid >> 6, lane = tid & 63;
  int quad = lane >> 4, l16 = lane & 15;
  int nt = blockIdx.x, b = blockIdx.y;
  int n0 = nt * 16;
  int h0 = wv * 16;
  f32x4 zz = {0.f, 0.f, 0.f, 0.f};
  f32x4 acc[12];
#pragma unroll
  for (int t = 0; t < 12; t++) acc[t] = zz;
#pragma unroll
  for (int ks = 0; ks < 4; ks++) {
    size_t aoff0 = (size_t)(n0 + l16) * MM + ks * 32 + quad * 8;
    bf16x8 a0h = *(const bf16x8*)(v1phi + aoff0);
    bf16x8 a0l = *(const bf16x8*)(v1plo + aoff0);
#pragma unroll
    for (int t = 0; t < 12; t++) {
      int j = t * 64 + h0 + l16;
      size_t boff = ((size_t)(b * 16 + ks * 4 + quad) * TC + j) * 8;
      bf16x8 bhv = *(const bf16x8*)(kvBhi + boff);
      bf16x8 blv = *(const bf16x8*)(kvBlo + boff);
      acc[t] = __builtin_amdgcn_mfma_f32_16x16x32_bf16(a0h, bhv, acc[t], 0, 0, 0);
      acc[t] = __builtin_amdgcn_mfma_f32_16x16x32_bf16(a0h, blv, acc[t], 0, 0, 0);
      acc[t] = __builtin_amdgcn_mfma_f32_16x16x32_bf16(a0l, bhv, acc[t], 0, 0, 0);
    }
  }
  int h = h0 + l16;
#pragma unroll
  for (int r = 0; r < 4; r++) {
    int n = n0 + quad * 4 + r;
    float idn = invden[n];
    float o[12];
#pragma unroll
    for (int t = 0; t < 12; t++) o[t] = acc[t][r] * idn;
    float* dst = out + ((size_t)(b * HH + h) * NN + n) * TT;
    *(float4*)(dst) = make_float4(o[0], o[1], o[2], o[3]);
    *(float4*)(dst + 4) = make_float4(o[4], o[5], o[6], o[7]);
    *(float4*)(dst + 8) = make_float4(o[8], o[9], o[10], o[11]);
  }
}

extern "C" void kernel_launch(void* const* d_in, const int* in_sizes, int n_in,
                              void* d_out, int out_size, void* d_ws, size_t ws_size,
                              hipStream_t stream) {
  const float* input = (const float*)d_in[0];
  const float* nv1   = (const float*)d_in[1];
  const float* nv2   = (const float*)d_in[2];
  const float* Wi    = (const float*)d_in[3];
  const float* bi    = (const float*)d_in[4];
  const float* Wo    = (const float*)d_in[5];
  const float* bo    = (const float*)d_in[6];
  const float* proj  = (const float*)d_in[7];
  float* out = (float*)d_out;
  float* v1p = out + V1OFF;
  float* v2p = out + V2OFF;
  // x hi/lo planes alias the out0 region exactly (50331648 shorts each)
  unsigned short* xhi = (unsigned short*)d_out;
  unsigned short* xlo = xhi + 50331648;

  char* wsb = (char*)d_ws;
  const size_t MB = 1 << 20;
  unsigned short* v2phiT = (unsigned short*)(wsb + 0 * MB);
  unsigned short* v2ploT = (unsigned short*)(wsb + 1 * MB);
  unsigned short* v1phi  = (unsigned short*)(wsb + 2 * MB);
  unsigned short* v1plo  = (unsigned short*)(wsb + 3 * MB);
  unsigned short* whi    = (unsigned short*)(wsb + 4 * MB);
  unsigned short* wlo    = (unsigned short*)(wsb + 4 * MB + 8192);
  float* colsum  = (float*)(wsb + 4 * MB + 16384);
  float* rowmax2 = (float*)(wsb + 4 * MB + 16384 + 512);
  float* stab2   = (float*)(wsb + 4 * MB + 16384 + 512 + 16384);
  float* invden  = (float*)(wsb + 5 * MB);
  unsigned short* kvBhi = (unsigned short*)(wsb + 6 * MB);
  unsigned short* kvBlo = (unsigned short*)(wsb + 10 * MB);
  float* kvpart = (float*)(wsb + 14 * MB);

  // adaptive n-split for kv partials based on available ws
  size_t partBytes = (size_t)BB * KVELEM * 4;
  size_t avail = (ws_size > 14 * MB) ? ws_size - 14 * MB : 0;
  int NS = (avail >= 8 * partBytes) ? 8 : (avail >= 4 * partBytes ? 4 : 2);

  hipMemsetAsync(colsum, 0, MM * sizeof(float), stream);
  k_wsplit<<<16, 256, 0, stream>>>(Wi, Wo, whi, wlo);
  k_feat<<<NN, 128, 0, stream>>>(nv1, nv2, proj, v1p, v2p, rowmax2, v1phi, v1plo);
  k_stab<<<1, 256, 0, stream>>>(rowmax2, stab2);
  k_v2p<<<64, 128, 0, stream>>>(v2p, stab2, colsum, v2phiT, v2ploT);
  k_den<<<16, 256, 0, stream>>>(v1p, colsum, invden);
  k_point<<<dim3(64, 16), 256, 0, stream>>>(input, whi, wlo, bi, bo, xhi, xlo);
  k_kv<<<dim3(12, NS, 16), 256, 0, stream>>>(xhi, xlo, v2phiT, v2ploT, kvpart);
  k_kvred<<<768, 256, 0, stream>>>(kvpart, kvBhi, kvBlo, NS);
  k_num<<<dim3(256, 16), 256, 0, stream>>>(v1phi, v1plo, kvBhi, kvBlo, invden, out);
}

// Round 6
// 677.469 us; speedup vs baseline: 1.0654x; 1.0654x over previous
//
#include <hip/hip_runtime.h>

#define BB 16
#define CIN 32
#define NN 4096
#define TT 12
#define HH 64
#define MM 128
#define DD 64
#define TC (TT*HH)            // 768
#define V1OFF 50331648        // B*H*N*T floats
#define V2OFF 50855936
#define KVELEM (MM*TC)        // 98304 per batch
#define NORMR 0.35355339059327373f   // 64^-0.25
#define RATIO 0.08838834764831845f   // 128^-0.5
#define FEPS 1e-4f

typedef __attribute__((ext_vector_type(8))) short bf16x8;
typedef __attribute__((ext_vector_type(4))) float f32x4;

union BF8 { unsigned short s[8]; bf16x8 v; };

__device__ inline float wave_max(float v) {
#pragma unroll
  for (int off = 32; off > 0; off >>= 1) v = fmaxf(v, __shfl_xor(v, off));
  return v;
}

__device__ inline unsigned short f2bf(float f) {
  unsigned int u = __float_as_uint(f);
  unsigned int r = (u + 0x7FFFu + ((u >> 16) & 1u)) >> 16;
  return (unsigned short)r;
}

// split float into hi/lo bf16 (hi + lo reconstructs to ~2^-17 rel)
__device__ inline void hilo(float v, unsigned short& h, unsigned short& l) {
  h = f2bf(v);
  float fh = __uint_as_float((unsigned int)h << 16);
  l = f2bf(v - fh);
}

// ---- tiny setup kernels -------------------------------------------------

// stack [Wi;Wo] into 128x32 and split hi/lo
__global__ __launch_bounds__(256) void k_wsplit(const float* __restrict__ Wi,
    const float* __restrict__ Wo, unsigned short* __restrict__ whi,
    unsigned short* __restrict__ wlo) {
  int idx = blockIdx.x * 256 + threadIdx.x;   // 4096
  int o = idx >> 5, c = idx & 31;
  float w = (o < 64) ? Wi[o * 32 + c] : Wo[(o - 64) * 32 + c];
  unsigned short h, l; hilo(w, h, l);
  whi[idx] = h; wlo[idx] = l;
}

// K1: per-row features. v1p final (+hi/lo planes); t2 = dash2-diag2 into v2p slot.
__global__ __launch_bounds__(128) void k_feat(const float* __restrict__ nv1,
    const float* __restrict__ nv2, const float* __restrict__ proj,
    float* __restrict__ v1p, float* __restrict__ t2, float* __restrict__ rowmax2,
    unsigned short* __restrict__ v1phi, unsigned short* __restrict__ v1plo) {
  int n = blockIdx.x, m = threadIdx.x;
  __shared__ float a1[DD], a2[DD], r1[2], r2[2];
  if (m < DD) a1[m] = nv1[n * DD + m];
  else        a2[m - DD] = nv2[n * DD + (m - DD)];
  __syncthreads();
  float s1 = 0.f, s2 = 0.f, d1 = 0.f, d2 = 0.f;
  const float* pr = proj + m * DD;
#pragma unroll 8
  for (int d = 0; d < DD; d++) {
    float x1 = a1[d], x2 = a2[d], p = pr[d];
    s1 += x1 * x1; s2 += x2 * x2;
    d1 += x1 * p;  d2 += x2 * p;
  }
  d1 *= NORMR; d2 *= NORMR;
  float diag1 = 0.0625f * s1, diag2 = 0.0625f * s2;
  float mx1 = wave_max(d1), mx2 = wave_max(d2);
  int wv = m >> 6;
  if ((m & 63) == 0) { r1[wv] = mx1; r2[wv] = mx2; }
  __syncthreads();
  mx1 = fmaxf(r1[0], r1[1]); mx2 = fmaxf(r2[0], r2[1]);
  float val = RATIO * (__expf(d1 - diag1 - mx1) + FEPS);
  v1p[n * MM + m] = val;
  unsigned short h, l; hilo(val, h, l);
  v1phi[n * MM + m] = h;
  v1plo[n * MM + m] = l;
  t2[n * MM + m] = d2 - diag2;
  if (m == 0) rowmax2[n] = mx2;
}

// K2: global max of dash2
__global__ __launch_bounds__(256) void k_stab(const float* __restrict__ rowmax2,
                                              float* __restrict__ stab2) {
  int tid = threadIdx.x;
  float mx = -3.4e38f;
  for (int i = tid; i < NN; i += 256) mx = fmaxf(mx, rowmax2[i]);
  mx = wave_max(mx);
  __shared__ float r[4];
  if ((tid & 63) == 0) r[tid >> 6] = mx;
  __syncthreads();
  if (tid == 0) stab2[0] = fmaxf(fmaxf(r[0], r[1]), fmaxf(r[2], r[3]));
}

// K3: finish v2p in place, colsum, and write transposed hi/lo planes [m][n]
__global__ __launch_bounds__(128) void k_v2p(float* __restrict__ t2v2p,
    const float* __restrict__ stab2, float* __restrict__ colsum,
    unsigned short* __restrict__ v2phiT, unsigned short* __restrict__ v2ploT) {
  int m = threadIdx.x;
  float stab = stab2[0];
  float cs = 0.f;
  int n0 = blockIdx.x * 64;   // contiguous chunk for write-combining
  for (int i = 0; i < 64; i++) {
    int n = n0 + i;
    float v = RATIO * (__expf(t2v2p[n * MM + m] - stab) + FEPS);
    t2v2p[n * MM + m] = v;
    cs += v;
    unsigned short h, l; hilo(v, h, l);
    v2phiT[(size_t)m * NN + n] = h;
    v2ploT[(size_t)m * NN + n] = l;
  }
  atomicAdd(&colsum[m], cs);
}

// K4: inv_den[n] = 1 / (v1p[n,:] . colsum)
__global__ __launch_bounds__(256) void k_den(const float* __restrict__ v1p,
    const float* __restrict__ colsum, float* __restrict__ invden) {
  __shared__ float cs[MM];
  int tid = threadIdx.x;
  if (tid < MM) cs[tid] = colsum[tid];
  __syncthreads();
  int n = blockIdx.x * 256 + tid;
  const float* vp = v1p + (size_t)n * MM;
  float s = 0.f;
#pragma unroll 8
  for (int m = 0; m < MM; m++) s += vp[m] * cs[m];
  invden[n] = 1.0f / s;
}

// ---- K5: conv+gate via MFMA. A = stacked W[128x32] hi/lo (regs), B = input.
// x stored hi/lo bf16 planes, layout [b][n/8][j=t*64+h][n%8].
// Stream-once reads: each lane preloads its full 48B t-rows (3x float4)
// for all 8 channels, converts once to per-t bf16 hi/lo packs, then computes
// all 12 t out of registers.
__global__ __launch_bounds__(256) void k_point(const float* __restrict__ inp,
    const unsigned short* __restrict__ whi, const unsigned short* __restrict__ wlo,
    const float* __restrict__ bi, const float* __restrict__ bo,
    unsigned short* __restrict__ xhi, unsigned short* __restrict__ xlo) {
  int tid = threadIdx.x;
  int wv = tid >> 6, lane = tid & 63;
  int quad = lane >> 4, l16 = lane & 15;
  int b = blockIdx.y;
  int n = blockIdx.x * 64 + wv * 16 + l16;

  bf16x8 wh[8], wl[8];
#pragma unroll
  for (int tile = 0; tile < 8; tile++) {
    int m = tile * 16 + l16;
    wh[tile] = *(const bf16x8*)(whi + m * 32 + quad * 8);
    wl[tile] = *(const bf16x8*)(wlo + m * 32 + quad * 8);
  }
  f32x4 binit[8];
#pragma unroll
  for (int tile = 0; tile < 8; tile++) {
    const float* bp = (tile < 4) ? bi : bo;
#pragma unroll
    for (int r = 0; r < 4; r++)
      binit[tile][r] = bp[(tile & 3) * 16 + quad * 4 + r];
  }
  const float* ipb = inp + ((size_t)b * CIN + quad * 8) * (NN * TT) + (size_t)n * TT;

  // preload all 12 t for the 8 channels of this quad; convert once.
  BF8 xh[TT], xl[TT];
#pragma unroll
  for (int j = 0; j < 8; j++) {
    const float* rp = ipb + (size_t)j * (NN * TT);
    float4 r0 = *(const float4*)(rp + 0);
    float4 r1 = *(const float4*)(rp + 4);
    float4 r2 = *(const float4*)(rp + 8);
    float row[TT] = {r0.x, r0.y, r0.z, r0.w, r1.x, r1.y, r1.z, r1.w,
                     r2.x, r2.y, r2.z, r2.w};
#pragma unroll
    for (int t = 0; t < TT; t++) {
      unsigned short h, l; hilo(row[t], h, l);
      xh[t].s[j] = h; xl[t].s[j] = l;
    }
  }

  size_t xbase = ((size_t)(b * (NN / 8) + (n >> 3)) * TC) * 8 + (n & 7);
#pragma unroll
  for (int t = 0; t < TT; t++) {
    f32x4 acc[8];
#pragma unroll
    for (int tile = 0; tile < 8; tile++) acc[tile] = binit[tile];
#pragma unroll
    for (int tile = 0; tile < 8; tile++) {
      acc[tile] = __builtin_amdgcn_mfma_f32_16x16x32_bf16(wh[tile], xh[t].v, acc[tile], 0, 0, 0);
      acc[tile] = __builtin_amdgcn_mfma_f32_16x16x32_bf16(wh[tile], xl[t].v, acc[tile], 0, 0, 0);
      acc[tile] = __builtin_amdgcn_mfma_f32_16x16x32_bf16(wl[tile], xh[t].v, acc[tile], 0, 0, 0);
    }
#pragma unroll
    for (int i = 0; i < 4; i++) {
#pragma unroll
      for (int r = 0; r < 4; r++) {
        float h1 = acc[i][r], h2 = acc[i + 4][r];
        float g = h2 / (1.f + __expf(-h1));
        unsigned short gh, gl; hilo(g, gh, gl);
        int j = t * 64 + i * 16 + quad * 4 + r;
        xhi[xbase + (size_t)j * 8] = gh;
        xlo[xbase + (size_t)j * 8] = gl;
      }
    }
  }
}

// ---- K6: kv partials via MFMA. A = v2pT hi/lo, B = x hi/lo.
// grid (6 jt, NS, 16 b); wave handles all 8 m-tiles x 32 j (2 j-frags).
// ROUND-4 FORMULATION RESTORED VERBATIM. Round-5's j-split regressed
// (160->235 us): halving the j-tile halved A-reuse, doubling load
// instructions per MFMA in a latency-bound kernel. TLP now comes from
// the NS (k) split instead, which preserves the reuse structure exactly.
__global__ __launch_bounds__(256) void k_kv(const unsigned short* __restrict__ xhi,
    const unsigned short* __restrict__ xlo,
    const unsigned short* __restrict__ v2phiT, const unsigned short* __restrict__ v2ploT,
    float* __restrict__ kvpart) {
  int tid = threadIdx.x, wv = tid >> 6, lane = tid & 63;
  int quad = lane >> 4, l16 = lane & 15;
  int jt = blockIdx.x, nsI = blockIdx.y, b = blockIdx.z;
  int NS = gridDim.y, kPer = NN / NS;
  int j0 = jt * 128 + wv * 32;
  f32x4 zz = {0.f, 0.f, 0.f, 0.f};
  f32x4 acc[8][2];
#pragma unroll
  for (int t = 0; t < 8; t++) { acc[t][0] = zz; acc[t][1] = zz; }
  int kend = nsI * kPer + kPer;
  for (int k0 = nsI * kPer; k0 < kend; k0 += 32) {
    bf16x8 ah[8], al[8];
#pragma unroll
    for (int tile = 0; tile < 8; tile++) {
      size_t off = (size_t)(tile * 16 + l16) * NN + k0 + quad * 8;
      ah[tile] = *(const bf16x8*)(v2phiT + off);
      al[tile] = *(const bf16x8*)(v2ploT + off);
    }
    bf16x8 bh[2], bl[2];
#pragma unroll
    for (int jf = 0; jf < 2; jf++) {
      size_t off = ((size_t)(b * (NN / 8) + (k0 >> 3) + quad) * TC + j0 + jf * 16 + l16) * 8;
      bh[jf] = *(const bf16x8*)(xhi + off);
      bl[jf] = *(const bf16x8*)(xlo + off);
    }
#pragma unroll
    for (int tile = 0; tile < 8; tile++) {
#pragma unroll
      for (int jf = 0; jf < 2; jf++) {
        acc[tile][jf] = __builtin_amdgcn_mfma_f32_16x16x32_bf16(ah[tile], bh[jf], acc[tile][jf], 0, 0, 0);
        acc[tile][jf] = __builtin_amdgcn_mfma_f32_16x16x32_bf16(ah[tile], bl[jf], acc[tile][jf], 0, 0, 0);
        acc[tile][jf] = __builtin_amdgcn_mfma_f32_16x16x32_bf16(al[tile], bh[jf], acc[tile][jf], 0, 0, 0);
      }
    }
  }
  float* dst = kvpart + (size_t)(nsI * BB + b) * KVELEM;
#pragma unroll
  for (int tile = 0; tile < 8; tile++)
#pragma unroll
    for (int jf = 0; jf < 2; jf++)
#pragma unroll
      for (int r = 0; r < 4; r++)
        dst[(size_t)(tile * 16 + quad * 4 + r) * TC + j0 + jf * 16 + l16] = acc[tile][jf][r];
}

// K6b: reduce NS partials, emit kvB hi/lo planes [b][m/8][j][m%8]
__global__ __launch_bounds__(256) void k_kvred(const float* __restrict__ kvpart,
    unsigned short* __restrict__ kvBhi, unsigned short* __restrict__ kvBlo, int NS) {
  int gid = blockIdx.x * 256 + threadIdx.x;   // 196608
  int j = gid % TC; int rest = gid / TC; int mgrp = rest & 15; int b = rest >> 4;
  float s[8];
#pragma unroll
  for (int mi = 0; mi < 8; mi++) s[mi] = 0.f;
  for (int ns = 0; ns < NS; ns++) {
    const float* p = kvpart + ((size_t)(ns * BB + b) * MM + mgrp * 8) * TC + j;
#pragma unroll
    for (int mi = 0; mi < 8; mi++) s[mi] += p[(size_t)mi * TC];
  }
  unsigned short hs[8] __attribute__((aligned(16)));
  unsigned short ls[8] __attribute__((aligned(16)));
#pragma unroll
  for (int mi = 0; mi < 8; mi++) hilo(s[mi], hs[mi], ls[mi]);
  size_t off = ((size_t)(b * 16 + mgrp) * TC + j) * 8;
  *(uint4*)(kvBhi + off) = *(const uint4*)hs;
  *(uint4*)(kvBlo + off) = *(const uint4*)ls;
}

// ---- K7: num = v1p . kv via MFMA, scale by invden, write [B,H,N,T].
// grid (256 nt, 16 b); wave: 16 n x 16 h x all 12 t. (n-split version;
// t-split variant failed correctness twice — quarantined.)
__global__ __launch_bounds__(256) void k_num(const unsigned short* __restrict__ v1phi,
    const unsigned short* __restrict__ v1plo, const unsigned short* __restrict__ kvBhi,
    const unsigned short* __restrict__ kvBlo, const float* __restrict__ invden,
    float* __restrict__ out) {
  int tid = threadIdx.x, wv = tid >> 6, lane = tid & 63;
  int quad = lane >> 4, l16 = lane & 15;
  int nt = blockIdx.x, b = blockIdx.y;
  int n0 = nt * 16;
  int h0 = wv * 16;
  f32x4 zz = {0.f, 0.f, 0.f, 0.f};
  f32x4 acc[12];
#pragma unroll
  for (int t = 0; t < 12; t++) acc[t] = zz;
#pragma unroll
  for (int ks = 0; ks < 4; ks++) {
    size_t aoff0 = (size_t)(n0 + l16) * MM + ks * 32 + quad * 8;
    bf16x8 a0h = *(const bf16x8*)(v1phi + aoff0);
    bf16x8 a0l = *(const bf16x8*)(v1plo + aoff0);
#pragma unroll
    for (int t = 0; t < 12; t++) {
      int j = t * 64 + h0 + l16;
      size_t boff = ((size_t)(b * 16 + ks * 4 + quad) * TC + j) * 8;
      bf16x8 bhv = *(const bf16x8*)(kvBhi + boff);
      bf16x8 blv = *(const bf16x8*)(kvBlo + boff);
      acc[t] = __builtin_amdgcn_mfma_f32_16x16x32_bf16(a0h, bhv, acc[t], 0, 0, 0);
      acc[t] = __builtin_amdgcn_mfma_f32_16x16x32_bf16(a0h, blv, acc[t], 0, 0, 0);
      acc[t] = __builtin_amdgcn_mfma_f32_16x16x32_bf16(a0l, bhv, acc[t], 0, 0, 0);
    }
  }
  int h = h0 + l16;
#pragma unroll
  for (int r = 0; r < 4; r++) {
    int n = n0 + quad * 4 + r;
    float idn = invden[n];
    float o[12];
#pragma unroll
    for (int t = 0; t < 12; t++) o[t] = acc[t][r] * idn;
    float* dst = out + ((size_t)(b * HH + h) * NN + n) * TT;
    *(float4*)(dst) = make_float4(o[0], o[1], o[2], o[3]);
    *(float4*)(dst + 4) = make_float4(o[4], o[5], o[6], o[7]);
    *(float4*)(dst + 8) = make_float4(o[8], o[9], o[10], o[11]);
  }
}

extern "C" void kernel_launch(void* const* d_in, const int* in_sizes, int n_in,
                              void* d_out, int out_size, void* d_ws, size_t ws_size,
                              hipStream_t stream) {
  const float* input = (const float*)d_in[0];
  const float* nv1   = (const float*)d_in[1];
  const float* nv2   = (const float*)d_in[2];
  const float* Wi    = (const float*)d_in[3];
  const float* bi    = (const float*)d_in[4];
  const float* Wo    = (const float*)d_in[5];
  const float* bo    = (const float*)d_in[6];
  const float* proj  = (const float*)d_in[7];
  float* out = (float*)d_out;
  float* v1p = out + V1OFF;
  float* v2p = out + V2OFF;
  // x hi/lo planes alias the out0 region exactly (50331648 shorts each)
  unsigned short* xhi = (unsigned short*)d_out;
  unsigned short* xlo = xhi + 50331648;

  char* wsb = (char*)d_ws;
  const size_t MB = 1 << 20;
  unsigned short* v2phiT = (unsigned short*)(wsb + 0 * MB);
  unsigned short* v2ploT = (unsigned short*)(wsb + 1 * MB);
  unsigned short* v1phi  = (unsigned short*)(wsb + 2 * MB);
  unsigned short* v1plo  = (unsigned short*)(wsb + 3 * MB);
  unsigned short* whi    = (unsigned short*)(wsb + 4 * MB);
  unsigned short* wlo    = (unsigned short*)(wsb + 4 * MB + 8192);
  float* colsum  = (float*)(wsb + 4 * MB + 16384);
  float* rowmax2 = (float*)(wsb + 4 * MB + 16384 + 512);
  float* stab2   = (float*)(wsb + 4 * MB + 16384 + 512 + 16384);
  float* invden  = (float*)(wsb + 5 * MB);
  unsigned short* kvBhi = (unsigned short*)(wsb + 6 * MB);
  unsigned short* kvBlo = (unsigned short*)(wsb + 10 * MB);
  float* kvpart = (float*)(wsb + 14 * MB);

  // adaptive k-split for kv partials based on available ws (cap raised to 16:
  // k-split doubles TLP without changing per-wave load/MFMA mix; costs only
  // +NS*6.3MB of partial write+read traffic)
  size_t partBytes = (size_t)BB * KVELEM * 4;
  size_t avail = (ws_size > 14 * MB) ? ws_size - 14 * MB : 0;
  int NS = (avail >= 16 * partBytes) ? 16 :
           (avail >= 8 * partBytes) ? 8 : (avail >= 4 * partBytes ? 4 : 2);

  hipMemsetAsync(colsum, 0, MM * sizeof(float), stream);
  k_wsplit<<<16, 256, 0, stream>>>(Wi, Wo, whi, wlo);
  k_feat<<<NN, 128, 0, stream>>>(nv1, nv2, proj, v1p, v2p, rowmax2, v1phi, v1plo);
  k_stab<<<1, 256, 0, stream>>>(rowmax2, stab2);
  k_v2p<<<64, 128, 0, stream>>>(v2p, stab2, colsum, v2phiT, v2ploT);
  k_den<<<16, 256, 0, stream>>>(v1p, colsum, invden);
  k_point<<<dim3(64, 16), 256, 0, stream>>>(input, whi, wlo, bi, bo, xhi, xlo);
  k_kv<<<dim3(6, NS, 16), 256, 0, stream>>>(xhi, xlo, v2phiT, v2ploT, kvpart);
  k_kvred<<<768, 256, 0, stream>>>(kvpart, kvBhi, kvBlo, NS);
  k_num<<<dim3(256, 16), 256, 0, stream>>>(v1phi, v1plo, kvBhi, kvBlo, invden, out);
}

// Round 9
// 668.508 us; speedup vs baseline: 1.0796x; 1.0134x over previous
//
#include <hip/hip_runtime.h>

#define BB 16
#define CIN 32
#define NN 4096
#define TT 12
#define HH 64
#define MM 128
#define DD 64
#define TC (TT*HH)            // 768
#define V1OFF 50331648        // B*H*N*T floats
#define V2OFF 50855936
#define KVELEM (MM*TC)        // 98304 per batch
#define NORMR 0.35355339059327373f   // 64^-0.25
#define RATIO 0.08838834764831845f   // 128^-0.5
#define FEPS 1e-4f

typedef __attribute__((ext_vector_type(8))) short bf16x8;
typedef __attribute__((ext_vector_type(4))) float f32x4;

union BF8 { unsigned short s[8]; bf16x8 v; };

__device__ inline float wave_max(float v) {
#pragma unroll
  for (int off = 32; off > 0; off >>= 1) v = fmaxf(v, __shfl_xor(v, off));
  return v;
}

__device__ inline unsigned short f2bf(float f) {
  unsigned int u = __float_as_uint(f);
  unsigned int r = (u + 0x7FFFu + ((u >> 16) & 1u)) >> 16;
  return (unsigned short)r;
}

// split float into hi/lo bf16 (hi + lo reconstructs to ~2^-17 rel)
__device__ inline void hilo(float v, unsigned short& h, unsigned short& l) {
  h = f2bf(v);
  float fh = __uint_as_float((unsigned int)h << 16);
  l = f2bf(v - fh);
}

// ---- tiny setup kernels -------------------------------------------------

// stack [Wi;Wo] into 128x32 and split hi/lo
__global__ __launch_bounds__(256) void k_wsplit(const float* __restrict__ Wi,
    const float* __restrict__ Wo, unsigned short* __restrict__ whi,
    unsigned short* __restrict__ wlo) {
  int idx = blockIdx.x * 256 + threadIdx.x;   // 4096
  int o = idx >> 5, c = idx & 31;
  float w = (o < 64) ? Wi[o * 32 + c] : Wo[(o - 64) * 32 + c];
  unsigned short h, l; hilo(w, h, l);
  whi[idx] = h; wlo[idx] = l;
}

// K1: per-row features. v1p final (+hi/lo planes); t2 = dash2-diag2 into v2p slot.
__global__ __launch_bounds__(128) void k_feat(const float* __restrict__ nv1,
    const float* __restrict__ nv2, const float* __restrict__ proj,
    float* __restrict__ v1p, float* __restrict__ t2, float* __restrict__ rowmax2,
    unsigned short* __restrict__ v1phi, unsigned short* __restrict__ v1plo) {
  int n = blockIdx.x, m = threadIdx.x;
  __shared__ float a1[DD], a2[DD], r1[2], r2[2];
  if (m < DD) a1[m] = nv1[n * DD + m];
  else        a2[m - DD] = nv2[n * DD + (m - DD)];
  __syncthreads();
  float s1 = 0.f, s2 = 0.f, d1 = 0.f, d2 = 0.f;
  const float* pr = proj + m * DD;
#pragma unroll 8
  for (int d = 0; d < DD; d++) {
    float x1 = a1[d], x2 = a2[d], p = pr[d];
    s1 += x1 * x1; s2 += x2 * x2;
    d1 += x1 * p;  d2 += x2 * p;
  }
  d1 *= NORMR; d2 *= NORMR;
  float diag1 = 0.0625f * s1, diag2 = 0.0625f * s2;
  float mx1 = wave_max(d1), mx2 = wave_max(d2);
  int wv = m >> 6;
  if ((m & 63) == 0) { r1[wv] = mx1; r2[wv] = mx2; }
  __syncthreads();
  mx1 = fmaxf(r1[0], r1[1]); mx2 = fmaxf(r2[0], r2[1]);
  float val = RATIO * (__expf(d1 - diag1 - mx1) + FEPS);
  v1p[n * MM + m] = val;
  unsigned short h, l; hilo(val, h, l);
  v1phi[n * MM + m] = h;
  v1plo[n * MM + m] = l;
  t2[n * MM + m] = d2 - diag2;
  if (m == 0) rowmax2[n] = mx2;
}

// K2: global max of dash2
__global__ __launch_bounds__(256) void k_stab(const float* __restrict__ rowmax2,
                                              float* __restrict__ stab2) {
  int tid = threadIdx.x;
  float mx = -3.4e38f;
  for (int i = tid; i < NN; i += 256) mx = fmaxf(mx, rowmax2[i]);
  mx = wave_max(mx);
  __shared__ float r[4];
  if ((tid & 63) == 0) r[tid >> 6] = mx;
  __syncthreads();
  if (tid == 0) stab2[0] = fmaxf(fmaxf(r[0], r[1]), fmaxf(r[2], r[3]));
}

// K3: finish v2p in place, colsum, and write transposed hi/lo planes [m][n]
__global__ __launch_bounds__(128) void k_v2p(float* __restrict__ t2v2p,
    const float* __restrict__ stab2, float* __restrict__ colsum,
    unsigned short* __restrict__ v2phiT, unsigned short* __restrict__ v2ploT) {
  int m = threadIdx.x;
  float stab = stab2[0];
  float cs = 0.f;
  int n0 = blockIdx.x * 64;   // contiguous chunk for write-combining
  for (int i = 0; i < 64; i++) {
    int n = n0 + i;
    float v = RATIO * (__expf(t2v2p[n * MM + m] - stab) + FEPS);
    t2v2p[n * MM + m] = v;
    cs += v;
    unsigned short h, l; hilo(v, h, l);
    v2phiT[(size_t)m * NN + n] = h;
    v2ploT[(size_t)m * NN + n] = l;
  }
  atomicAdd(&colsum[m], cs);
}

// K4: inv_den[n] = 1 / (v1p[n,:] . colsum)
__global__ __launch_bounds__(256) void k_den(const float* __restrict__ v1p,
    const float* __restrict__ colsum, float* __restrict__ invden) {
  __shared__ float cs[MM];
  int tid = threadIdx.x;
  if (tid < MM) cs[tid] = colsum[tid];
  __syncthreads();
  int n = blockIdx.x * 256 + tid;
  const float* vp = v1p + (size_t)n * MM;
  float s = 0.f;
#pragma unroll 8
  for (int m = 0; m < MM; m++) s += vp[m] * cs[m];
  invden[n] = 1.0f / s;
}

// ---- K5: conv+gate via MFMA. A = stacked W[128x32] hi/lo (regs), B = input.
// x stored hi/lo bf16 planes, layout [b][n/8][j=t*64+h][n%8].
// t-split 3-way (4 t per block): shrinks per-block packs 96->32 VGPR and
// triples block-level TLP (was VGPR 144, 11% occ, all pipes idle =
// latency-bound). WRITE-RACE SAFETY: each block's x-plane region per
// (b, n/8) group is j in [t0*64, t0*64+256) = a 4KB-aligned disjoint
// chunk — no 64B line is shared between blocks. (Round-2/3 k_num t-split
// failure root-cause: 16B-granular inter-block write interleaving within
// one 64B line races across non-coherent per-XCD L2s. Never partition
// output below 64B-line granularity.)
__global__ __launch_bounds__(256) void k_point(const float* __restrict__ inp,
    const unsigned short* __restrict__ whi, const unsigned short* __restrict__ wlo,
    const float* __restrict__ bi, const float* __restrict__ bo,
    unsigned short* __restrict__ xhi, unsigned short* __restrict__ xlo) {
  int tid = threadIdx.x;
  int wv = tid >> 6, lane = tid & 63;
  int quad = lane >> 4, l16 = lane & 15;
  int b = blockIdx.y;
  int t0 = blockIdx.z * 4;              // {0,4,8}: float4 at +t0 stays 16B-aligned
  int n = blockIdx.x * 64 + wv * 16 + l16;

  bf16x8 wh[8], wl[8];
#pragma unroll
  for (int tile = 0; tile < 8; tile++) {
    int m = tile * 16 + l16;
    wh[tile] = *(const bf16x8*)(whi + m * 32 + quad * 8);
    wl[tile] = *(const bf16x8*)(wlo + m * 32 + quad * 8);
  }
  f32x4 binit[8];
#pragma unroll
  for (int tile = 0; tile < 8; tile++) {
    const float* bp = (tile < 4) ? bi : bo;
#pragma unroll
    for (int r = 0; r < 4; r++)
      binit[tile][r] = bp[(tile & 3) * 16 + quad * 4 + r];
  }
  const float* ipb = inp + ((size_t)b * CIN + quad * 8) * (NN * TT) + (size_t)n * TT + t0;

  // preload this block's 4 t for the 8 channels of this quad; convert once.
  BF8 xh[4], xl[4];
#pragma unroll
  for (int j = 0; j < 8; j++) {
    float4 r0 = *(const float4*)(ipb + (size_t)j * (NN * TT));
    float row[4] = {r0.x, r0.y, r0.z, r0.w};
#pragma unroll
    for (int tt = 0; tt < 4; tt++) {
      unsigned short h, l; hilo(row[tt], h, l);
      xh[tt].s[j] = h; xl[tt].s[j] = l;
    }
  }

  size_t xbase = ((size_t)(b * (NN / 8) + (n >> 3)) * TC) * 8 + (n & 7);
#pragma unroll
  for (int tt = 0; tt < 4; tt++) {
    int t = t0 + tt;
    f32x4 acc[8];
#pragma unroll
    for (int tile = 0; tile < 8; tile++) acc[tile] = binit[tile];
#pragma unroll
    for (int tile = 0; tile < 8; tile++) {
      acc[tile] = __builtin_amdgcn_mfma_f32_16x16x32_bf16(wh[tile], xh[tt].v, acc[tile], 0, 0, 0);
      acc[tile] = __builtin_amdgcn_mfma_f32_16x16x32_bf16(wh[tile], xl[tt].v, acc[tile], 0, 0, 0);
      acc[tile] = __builtin_amdgcn_mfma_f32_16x16x32_bf16(wl[tile], xh[tt].v, acc[tile], 0, 0, 0);
    }
#pragma unroll
    for (int i = 0; i < 4; i++) {
#pragma unroll
      for (int r = 0; r < 4; r++) {
        float h1 = acc[i][r], h2 = acc[i + 4][r];
        float g = h2 / (1.f + __expf(-h1));
        unsigned short gh, gl; hilo(g, gh, gl);
        int j = t * 64 + i * 16 + quad * 4 + r;
        xhi[xbase + (size_t)j * 8] = gh;
        xlo[xbase + (size_t)j * 8] = gl;
      }
    }
  }
}

// ---- K6: kv partials via MFMA. A = v2pT hi/lo, B = x hi/lo.
// grid (6 jt, NS, 16 b); wave handles all 8 m-tiles x 32 j (2 j-frags).
// (Round-5's j-split regressed: halving the j-tile halved A-reuse,
// doubling load instructions per MFMA. TLP comes from the NS k-split,
// which preserves the reuse structure exactly.)
__global__ __launch_bounds__(256) void k_kv(const unsigned short* __restrict__ xhi,
    const unsigned short* __restrict__ xlo,
    const unsigned short* __restrict__ v2phiT, const unsigned short* __restrict__ v2ploT,
    float* __restrict__ kvpart) {
  int tid = threadIdx.x, wv = tid >> 6, lane = tid & 63;
  int quad = lane >> 4, l16 = lane & 15;
  int jt = blockIdx.x, nsI = blockIdx.y, b = blockIdx.z;
  int NS = gridDim.y, kPer = NN / NS;
  int j0 = jt * 128 + wv * 32;
  f32x4 zz = {0.f, 0.f, 0.f, 0.f};
  f32x4 acc[8][2];
#pragma unroll
  for (int t = 0; t < 8; t++) { acc[t][0] = zz; acc[t][1] = zz; }
  int kend = nsI * kPer + kPer;
  for (int k0 = nsI * kPer; k0 < kend; k0 += 32) {
    bf16x8 ah[8], al[8];
#pragma unroll
    for (int tile = 0; tile < 8; tile++) {
      size_t off = (size_t)(tile * 16 + l16) * NN + k0 + quad * 8;
      ah[tile] = *(const bf16x8*)(v2phiT + off);
      al[tile] = *(const bf16x8*)(v2ploT + off);
    }
    bf16x8 bh[2], bl[2];
#pragma unroll
    for (int jf = 0; jf < 2; jf++) {
      size_t off = ((size_t)(b * (NN / 8) + (k0 >> 3) + quad) * TC + j0 + jf * 16 + l16) * 8;
      bh[jf] = *(const bf16x8*)(xhi + off);
      bl[jf] = *(const bf16x8*)(xlo + off);
    }
#pragma unroll
    for (int tile = 0; tile < 8; tile++) {
#pragma unroll
      for (int jf = 0; jf < 2; jf++) {
        acc[tile][jf] = __builtin_amdgcn_mfma_f32_16x16x32_bf16(ah[tile], bh[jf], acc[tile][jf], 0, 0, 0);
        acc[tile][jf] = __builtin_amdgcn_mfma_f32_16x16x32_bf16(ah[tile], bl[jf], acc[tile][jf], 0, 0, 0);
        acc[tile][jf] = __builtin_amdgcn_mfma_f32_16x16x32_bf16(al[tile], bh[jf], acc[tile][jf], 0, 0, 0);
      }
    }
  }
  float* dst = kvpart + (size_t)(nsI * BB + b) * KVELEM;
#pragma unroll
  for (int tile = 0; tile < 8; tile++)
#pragma unroll
    for (int jf = 0; jf < 2; jf++)
#pragma unroll
      for (int r = 0; r < 4; r++)
        dst[(size_t)(tile * 16 + quad * 4 + r) * TC + j0 + jf * 16 + l16] = acc[tile][jf][r];
}

// K6b: reduce NS partials, emit kvB hi/lo planes [b][m/8][j][m%8]
__global__ __launch_bounds__(256) void k_kvred(const float* __restrict__ kvpart,
    unsigned short* __restrict__ kvBhi, unsigned short* __restrict__ kvBlo, int NS) {
  int gid = blockIdx.x * 256 + threadIdx.x;   // 196608
  int j = gid % TC; int rest = gid / TC; int mgrp = rest & 15; int b = rest >> 4;
  float s[8];
#pragma unroll
  for (int mi = 0; mi < 8; mi++) s[mi] = 0.f;
  for (int ns = 0; ns < NS; ns++) {
    const float* p = kvpart + ((size_t)(ns * BB + b) * MM + mgrp * 8) * TC + j;
#pragma unroll
    for (int mi = 0; mi < 8; mi++) s[mi] += p[(size_t)mi * TC];
  }
  unsigned short hs[8] __attribute__((aligned(16)));
  unsigned short ls[8] __attribute__((aligned(16)));
#pragma unroll
  for (int mi = 0; mi < 8; mi++) hilo(s[mi], hs[mi], ls[mi]);
  size_t off = ((size_t)(b * 16 + mgrp) * TC + j) * 8;
  *(uint4*)(kvBhi + off) = *(const uint4*)hs;
  *(uint4*)(kvBlo + off) = *(const uint4*)ls;
}

// ---- K7: num = v1p . kv via MFMA, scale by invden, write [B,H,N,T].
// grid (256 nt, 16 b); wave: 16 n x 16 h x all 12 t. n-split: per-block
// output chunks are 768B (64B-line-aligned) — no cross-block line sharing.
__global__ __launch_bounds__(256) void k_num(const unsigned short* __restrict__ v1phi,
    const unsigned short* __restrict__ v1plo, const unsigned short* __restrict__ kvBhi,
    const unsigned short* __restrict__ kvBlo, const float* __restrict__ invden,
    float* __restrict__ out) {
  int tid = threadIdx.x, wv = tid >> 6, lane = tid & 63;
  int quad = lane >> 4, l16 = lane & 15;
  int nt = blockIdx.x, b = blockIdx.y;
  int n0 = nt * 16;
  int h0 = wv * 16;
  f32x4 zz = {0.f, 0.f, 0.f, 0.f};
  f32x4 acc[12];
#pragma unroll
  for (int t = 0; t < 12; t++) acc[t] = zz;
#pragma unroll
  for (int ks = 0; ks < 4; ks++) {
    size_t aoff0 = (size_t)(n0 + l16) * MM + ks * 32 + quad * 8;
    bf16x8 a0h = *(const bf16x8*)(v1phi + aoff0);
    bf16x8 a0l = *(const bf16x8*)(v1plo + aoff0);
#pragma unroll
    for (int t = 0; t < 12; t++) {
      int j = t * 64 + h0 + l16;
      size_t boff = ((size_t)(b * 16 + ks * 4 + quad) * TC + j) * 8;
      bf16x8 bhv = *(const bf16x8*)(kvBhi + boff);
      bf16x8 blv = *(const bf16x8*)(kvBlo + boff);
      acc[t] = __builtin_amdgcn_mfma_f32_16x16x32_bf16(a0h, bhv, acc[t], 0, 0, 0);
      acc[t] = __builtin_amdgcn_mfma_f32_16x16x32_bf16(a0h, blv, acc[t], 0, 0, 0);
      acc[t] = __builtin_amdgcn_mfma_f32_16x16x32_bf16(a0l, bhv, acc[t], 0, 0, 0);
    }
  }
  int h = h0 + l16;
#pragma unroll
  for (int r = 0; r < 4; r++) {
    int n = n0 + quad * 4 + r;
    float idn = invden[n];
    float o[12];
#pragma unroll
    for (int t = 0; t < 12; t++) o[t] = acc[t][r] * idn;
    float* dst = out + ((size_t)(b * HH + h) * NN + n) * TT;
    *(float4*)(dst) = make_float4(o[0], o[1], o[2], o[3]);
    *(float4*)(dst + 4) = make_float4(o[4], o[5], o[6], o[7]);
    *(float4*)(dst + 8) = make_float4(o[8], o[9], o[10], o[11]);
  }
}

extern "C" void kernel_launch(void* const* d_in, const int* in_sizes, int n_in,
                              void* d_out, int out_size, void* d_ws, size_t ws_size,
                              hipStream_t stream) {
  const float* input = (const float*)d_in[0];
  const float* nv1   = (const float*)d_in[1];
  const float* nv2   = (const float*)d_in[2];
  const float* Wi    = (const float*)d_in[3];
  const float* bi    = (const float*)d_in[4];
  const float* Wo    = (const float*)d_in[5];
  const float* bo    = (const float*)d_in[6];
  const float* proj  = (const float*)d_in[7];
  float* out = (float*)d_out;
  float* v1p = out + V1OFF;
  float* v2p = out + V2OFF;
  // x hi/lo planes alias the out0 region exactly (50331648 shorts each)
  unsigned short* xhi = (unsigned short*)d_out;
  unsigned short* xlo = xhi + 50331648;

  char* wsb = (char*)d_ws;
  const size_t MB = 1 << 20;
  unsigned short* v2phiT = (unsigned short*)(wsb + 0 * MB);
  unsigned short* v2ploT = (unsigned short*)(wsb + 1 * MB);
  unsigned short* v1phi  = (unsigned short*)(wsb + 2 * MB);
  unsigned short* v1plo  = (unsigned short*)(wsb + 3 * MB);
  unsigned short* whi    = (unsigned short*)(wsb + 4 * MB);
  unsigned short* wlo    = (unsigned short*)(wsb + 4 * MB + 8192);
  float* colsum  = (float*)(wsb + 4 * MB + 16384);
  float* rowmax2 = (float*)(wsb + 4 * MB + 16384 + 512);
  float* stab2   = (float*)(wsb + 4 * MB + 16384 + 512 + 16384);
  float* invden  = (float*)(wsb + 5 * MB);
  unsigned short* kvBhi = (unsigned short*)(wsb + 6 * MB);
  unsigned short* kvBlo = (unsigned short*)(wsb + 10 * MB);
  float* kvpart = (float*)(wsb + 14 * MB);

  // adaptive k-split for kv partials based on available ws
  size_t partBytes = (size_t)BB * KVELEM * 4;
  size_t avail = (ws_size > 14 * MB) ? ws_size - 14 * MB : 0;
  int NS = (avail >= 16 * partBytes) ? 16 :
           (avail >= 8 * partBytes) ? 8 : (avail >= 4 * partBytes ? 4 : 2);

  hipMemsetAsync(colsum, 0, MM * sizeof(float), stream);
  k_wsplit<<<16, 256, 0, stream>>>(Wi, Wo, whi, wlo);
  k_feat<<<NN, 128, 0, stream>>>(nv1, nv2, proj, v1p, v2p, rowmax2, v1phi, v1plo);
  k_stab<<<1, 256, 0, stream>>>(rowmax2, stab2);
  k_v2p<<<64, 128, 0, stream>>>(v2p, stab2, colsum, v2phiT, v2ploT);
  k_den<<<16, 256, 0, stream>>>(v1p, colsum, invden);
  k_point<<<dim3(64, 16, 3), 256, 0, stream>>>(input, whi, wlo, bi, bo, xhi, xlo);
  k_kv<<<dim3(6, NS, 16), 256, 0, stream>>>(xhi, xlo, v2phiT, v2ploT, kvpart);
  k_kvred<<<768, 256, 0, stream>>>(kvpart, kvBhi, kvBlo, NS);
  k_num<<<dim3(256, 16), 256, 0, stream>>>(v1phi, v1plo, kvBhi, kvBlo, invden, out);
}

// Round 10
// 656.936 us; speedup vs baseline: 1.0987x; 1.0176x over previous
//
#include <hip/hip_runtime.h>

#define BB 16
#define CIN 32
#define NN 4096
#define TT 12
#define HH 64
#define MM 128
#define DD 64
#define TC (TT*HH)            // 768
#define V1OFF 50331648        // B*H*N*T floats
#define V2OFF 50855936
#define KVELEM (MM*TC)        // 98304 per batch
#define NORMR 0.35355339059327373f   // 64^-0.25
#define RATIO 0.08838834764831845f   // 128^-0.5
#define FEPS 1e-4f

typedef __attribute__((ext_vector_type(8))) short bf16x8;
typedef __attribute__((ext_vector_type(4))) float f32x4;

union BF8 { unsigned short s[8]; bf16x8 v; };

__device__ inline float wave_max(float v) {
#pragma unroll
  for (int off = 32; off > 0; off >>= 1) v = fmaxf(v, __shfl_xor(v, off));
  return v;
}

__device__ inline unsigned short f2bf(float f) {
  unsigned int u = __float_as_uint(f);
  unsigned int r = (u + 0x7FFFu + ((u >> 16) & 1u)) >> 16;
  return (unsigned short)r;
}

// split float into hi/lo bf16 (hi + lo reconstructs to ~2^-17 rel)
__device__ inline void hilo(float v, unsigned short& h, unsigned short& l) {
  h = f2bf(v);
  float fh = __uint_as_float((unsigned int)h << 16);
  l = f2bf(v - fh);
}

// ---- tiny setup kernels -------------------------------------------------

// stack [Wi;Wo] into 128x32 and split hi/lo
__global__ __launch_bounds__(256) void k_wsplit(const float* __restrict__ Wi,
    const float* __restrict__ Wo, unsigned short* __restrict__ whi,
    unsigned short* __restrict__ wlo) {
  int idx = blockIdx.x * 256 + threadIdx.x;   // 4096
  int o = idx >> 5, c = idx & 31;
  float w = (o < 64) ? Wi[o * 32 + c] : Wo[(o - 64) * 32 + c];
  unsigned short h, l; hilo(w, h, l);
  whi[idx] = h; wlo[idx] = l;
}

// K1: per-row features. v1p final (+hi/lo planes); t2 = dash2-diag2 into v2p slot.
__global__ __launch_bounds__(128) void k_feat(const float* __restrict__ nv1,
    const float* __restrict__ nv2, const float* __restrict__ proj,
    float* __restrict__ v1p, float* __restrict__ t2, float* __restrict__ rowmax2,
    unsigned short* __restrict__ v1phi, unsigned short* __restrict__ v1plo) {
  int n = blockIdx.x, m = threadIdx.x;
  __shared__ float a1[DD], a2[DD], r1[2], r2[2];
  if (m < DD) a1[m] = nv1[n * DD + m];
  else        a2[m - DD] = nv2[n * DD + (m - DD)];
  __syncthreads();
  float s1 = 0.f, s2 = 0.f, d1 = 0.f, d2 = 0.f;
  const float* pr = proj + m * DD;
#pragma unroll 8
  for (int d = 0; d < DD; d++) {
    float x1 = a1[d], x2 = a2[d], p = pr[d];
    s1 += x1 * x1; s2 += x2 * x2;
    d1 += x1 * p;  d2 += x2 * p;
  }
  d1 *= NORMR; d2 *= NORMR;
  float diag1 = 0.0625f * s1, diag2 = 0.0625f * s2;
  float mx1 = wave_max(d1), mx2 = wave_max(d2);
  int wv = m >> 6;
  if ((m & 63) == 0) { r1[wv] = mx1; r2[wv] = mx2; }
  __syncthreads();
  mx1 = fmaxf(r1[0], r1[1]); mx2 = fmaxf(r2[0], r2[1]);
  float val = RATIO * (__expf(d1 - diag1 - mx1) + FEPS);
  v1p[n * MM + m] = val;
  unsigned short h, l; hilo(val, h, l);
  v1phi[n * MM + m] = h;
  v1plo[n * MM + m] = l;
  t2[n * MM + m] = d2 - diag2;
  if (m == 0) rowmax2[n] = mx2;
}

// K2: global max of dash2
__global__ __launch_bounds__(256) void k_stab(const float* __restrict__ rowmax2,
                                              float* __restrict__ stab2) {
  int tid = threadIdx.x;
  float mx = -3.4e38f;
  for (int i = tid; i < NN; i += 256) mx = fmaxf(mx, rowmax2[i]);
  mx = wave_max(mx);
  __shared__ float r[4];
  if ((tid & 63) == 0) r[tid >> 6] = mx;
  __syncthreads();
  if (tid == 0) stab2[0] = fmaxf(fmaxf(r[0], r[1]), fmaxf(r[2], r[3]));
}

// K3: finish v2p in place, colsum, and write transposed hi/lo planes [m][n]
__global__ __launch_bounds__(128) void k_v2p(float* __restrict__ t2v2p,
    const float* __restrict__ stab2, float* __restrict__ colsum,
    unsigned short* __restrict__ v2phiT, unsigned short* __restrict__ v2ploT) {
  int m = threadIdx.x;
  float stab = stab2[0];
  float cs = 0.f;
  int n0 = blockIdx.x * 64;   // contiguous chunk for write-combining
  for (int i = 0; i < 64; i++) {
    int n = n0 + i;
    float v = RATIO * (__expf(t2v2p[n * MM + m] - stab) + FEPS);
    t2v2p[n * MM + m] = v;
    cs += v;
    unsigned short h, l; hilo(v, h, l);
    v2phiT[(size_t)m * NN + n] = h;
    v2ploT[(size_t)m * NN + n] = l;
  }
  atomicAdd(&colsum[m], cs);
}

// K4: inv_den[n] = 1 / (v1p[n,:] . colsum)
__global__ __launch_bounds__(256) void k_den(const float* __restrict__ v1p,
    const float* __restrict__ colsum, float* __restrict__ invden) {
  __shared__ float cs[MM];
  int tid = threadIdx.x;
  if (tid < MM) cs[tid] = colsum[tid];
  __syncthreads();
  int n = blockIdx.x * 256 + tid;
  const float* vp = v1p + (size_t)n * MM;
  float s = 0.f;
#pragma unroll 8
  for (int m = 0; m < MM; m++) s += vp[m] * cs[m];
  invden[n] = 1.0f / s;
}

// ---- K5: conv+gate via MFMA. A = stacked W[128x32] hi/lo (regs), B = input.
// x stored hi/lo bf16 planes, layout [b][n/8][j=t*64+h][n%8].
// t-split 3-way (4 t per block); stream-once reads; 4KB-aligned disjoint
// write chunks per block (64B-line rule).
__global__ __launch_bounds__(256) void k_point(const float* __restrict__ inp,
    const unsigned short* __restrict__ whi, const unsigned short* __restrict__ wlo,
    const float* __restrict__ bi, const float* __restrict__ bo,
    unsigned short* __restrict__ xhi, unsigned short* __restrict__ xlo) {
  int tid = threadIdx.x;
  int wv = tid >> 6, lane = tid & 63;
  int quad = lane >> 4, l16 = lane & 15;
  int b = blockIdx.y;
  int t0 = blockIdx.z * 4;              // {0,4,8}: float4 at +t0 stays 16B-aligned
  int n = blockIdx.x * 64 + wv * 16 + l16;

  bf16x8 wh[8], wl[8];
#pragma unroll
  for (int tile = 0; tile < 8; tile++) {
    int m = tile * 16 + l16;
    wh[tile] = *(const bf16x8*)(whi + m * 32 + quad * 8);
    wl[tile] = *(const bf16x8*)(wlo + m * 32 + quad * 8);
  }
  f32x4 binit[8];
#pragma unroll
  for (int tile = 0; tile < 8; tile++) {
    const float* bp = (tile < 4) ? bi : bo;
#pragma unroll
    for (int r = 0; r < 4; r++)
      binit[tile][r] = bp[(tile & 3) * 16 + quad * 4 + r];
  }
  const float* ipb = inp + ((size_t)b * CIN + quad * 8) * (NN * TT) + (size_t)n * TT + t0;

  // preload this block's 4 t for the 8 channels of this quad; convert once.
  BF8 xh[4], xl[4];
#pragma unroll
  for (int j = 0; j < 8; j++) {
    float4 r0 = *(const float4*)(ipb + (size_t)j * (NN * TT));
    float row[4] = {r0.x, r0.y, r0.z, r0.w};
#pragma unroll
    for (int tt = 0; tt < 4; tt++) {
      unsigned short h, l; hilo(row[tt], h, l);
      xh[tt].s[j] = h; xl[tt].s[j] = l;
    }
  }

  size_t xbase = ((size_t)(b * (NN / 8) + (n >> 3)) * TC) * 8 + (n & 7);
#pragma unroll
  for (int tt = 0; tt < 4; tt++) {
    int t = t0 + tt;
    f32x4 acc[8];
#pragma unroll
    for (int tile = 0; tile < 8; tile++) acc[tile] = binit[tile];
#pragma unroll
    for (int tile = 0; tile < 8; tile++) {
      acc[tile] = __builtin_amdgcn_mfma_f32_16x16x32_bf16(wh[tile], xh[tt].v, acc[tile], 0, 0, 0);
      acc[tile] = __builtin_amdgcn_mfma_f32_16x16x32_bf16(wh[tile], xl[tt].v, acc[tile], 0, 0, 0);
      acc[tile] = __builtin_amdgcn_mfma_f32_16x16x32_bf16(wl[tile], xh[tt].v, acc[tile], 0, 0, 0);
    }
#pragma unroll
    for (int i = 0; i < 4; i++) {
#pragma unroll
      for (int r = 0; r < 4; r++) {
        float h1 = acc[i][r], h2 = acc[i + 4][r];
        float g = h2 / (1.f + __expf(-h1));
        unsigned short gh, gl; hilo(g, gh, gl);
        int j = t * 64 + i * 16 + quad * 4 + r;
        xhi[xbase + (size_t)j * 8] = gh;
        xlo[xbase + (size_t)j * 8] = gl;
      }
    }
  }
}

// ---- K6: kv partials via MFMA. A = v2pT hi/lo, B = x hi/lo.
// grid (6 jt, NS, 16 b); wave handles all 8 m-tiles x 32 j (2 j-frags).
// (j-split regressed — halved A-reuse; TLP comes from the NS k-split.)
__global__ __launch_bounds__(256) void k_kv(const unsigned short* __restrict__ xhi,
    const unsigned short* __restrict__ xlo,
    const unsigned short* __restrict__ v2phiT, const unsigned short* __restrict__ v2ploT,
    float* __restrict__ kvpart) {
  int tid = threadIdx.x, wv = tid >> 6, lane = tid & 63;
  int quad = lane >> 4, l16 = lane & 15;
  int jt = blockIdx.x, nsI = blockIdx.y, b = blockIdx.z;
  int NS = gridDim.y, kPer = NN / NS;
  int j0 = jt * 128 + wv * 32;
  f32x4 zz = {0.f, 0.f, 0.f, 0.f};
  f32x4 acc[8][2];
#pragma unroll
  for (int t = 0; t < 8; t++) { acc[t][0] = zz; acc[t][1] = zz; }
  int kend = nsI * kPer + kPer;
  for (int k0 = nsI * kPer; k0 < kend; k0 += 32) {
    bf16x8 ah[8], al[8];
#pragma unroll
    for (int tile = 0; tile < 8; tile++) {
      size_t off = (size_t)(tile * 16 + l16) * NN + k0 + quad * 8;
      ah[tile] = *(const bf16x8*)(v2phiT + off);
      al[tile] = *(const bf16x8*)(v2ploT + off);
    }
    bf16x8 bh[2], bl[2];
#pragma unroll
    for (int jf = 0; jf < 2; jf++) {
      size_t off = ((size_t)(b * (NN / 8) + (k0 >> 3) + quad) * TC + j0 + jf * 16 + l16) * 8;
      bh[jf] = *(const bf16x8*)(xhi + off);
      bl[jf] = *(const bf16x8*)(xlo + off);
    }
#pragma unroll
    for (int tile = 0; tile < 8; tile++) {
#pragma unroll
      for (int jf = 0; jf < 2; jf++) {
        acc[tile][jf] = __builtin_amdgcn_mfma_f32_16x16x32_bf16(ah[tile], bh[jf], acc[tile][jf], 0, 0, 0);
        acc[tile][jf] = __builtin_amdgcn_mfma_f32_16x16x32_bf16(ah[tile], bl[jf], acc[tile][jf], 0, 0, 0);
        acc[tile][jf] = __builtin_amdgcn_mfma_f32_16x16x32_bf16(al[tile], bh[jf], acc[tile][jf], 0, 0, 0);
      }
    }
  }
  float* dst = kvpart + (size_t)(nsI * BB + b) * KVELEM;
#pragma unroll
  for (int tile = 0; tile < 8; tile++)
#pragma unroll
    for (int jf = 0; jf < 2; jf++)
#pragma unroll
      for (int r = 0; r < 4; r++)
        dst[(size_t)(tile * 16 + quad * 4 + r) * TC + j0 + jf * 16 + l16] = acc[tile][jf][r];
}

// K6b: reduce NS partials, emit kvB hi/lo planes [b][m/8][j][m%8]
__global__ __launch_bounds__(256) void k_kvred(const float* __restrict__ kvpart,
    unsigned short* __restrict__ kvBhi, unsigned short* __restrict__ kvBlo, int NS) {
  int gid = blockIdx.x * 256 + threadIdx.x;   // 196608
  int j = gid % TC; int rest = gid / TC; int mgrp = rest & 15; int b = rest >> 4;
  float s[8];
#pragma unroll
  for (int mi = 0; mi < 8; mi++) s[mi] = 0.f;
  for (int ns = 0; ns < NS; ns++) {
    const float* p = kvpart + ((size_t)(ns * BB + b) * MM + mgrp * 8) * TC + j;
#pragma unroll
    for (int mi = 0; mi < 8; mi++) s[mi] += p[(size_t)mi * TC];
  }
  unsigned short hs[8] __attribute__((aligned(16)));
  unsigned short ls[8] __attribute__((aligned(16)));
#pragma unroll
  for (int mi = 0; mi < 8; mi++) hilo(s[mi], hs[mi], ls[mi]);
  size_t off = ((size_t)(b * 16 + mgrp) * TC + j) * 8;
  *(uint4*)(kvBhi + off) = *(const uint4*)hs;
  *(uint4*)(kvBlo + off) = *(const uint4*)ls;
}

// ---- K7: num = v1p . kv via MFMA, scale by invden, write [B,H,N,T].
// grid (256 nt, 16 b); wave: 16 n x 16 h x all 12 t.
// SWAPPED-OPERAND MFMA: mfma(kvB_frag, v1p_frag) — A/B fragments have
// identical lane layouts (free-dim=l16, k=quad*8+reg), so the same
// registers serve both roles; D comes out transposed: col=l16 <-> n,
// row=quad*4+r <-> h. Store now has 16 lanes covering 16 CONSECUTIVE n
// (768B contiguous per quarter-wave) instead of 16 lines spread over
// 196KB — ~5x fewer cache lines per store instruction. (Was 1.64 TB/s,
// occ 28.6%, MFMA ~5us: write line-scatter was the remaining suspect.)
__global__ __launch_bounds__(256) void k_num(const unsigned short* __restrict__ v1phi,
    const unsigned short* __restrict__ v1plo, const unsigned short* __restrict__ kvBhi,
    const unsigned short* __restrict__ kvBlo, const float* __restrict__ invden,
    float* __restrict__ out) {
  int tid = threadIdx.x, wv = tid >> 6, lane = tid & 63;
  int quad = lane >> 4, l16 = lane & 15;
  int nt = blockIdx.x, b = blockIdx.y;
  int n0 = nt * 16;
  int h0 = wv * 16;
  f32x4 zz = {0.f, 0.f, 0.f, 0.f};
  f32x4 acc[12];
#pragma unroll
  for (int t = 0; t < 12; t++) acc[t] = zz;
#pragma unroll
  for (int ks = 0; ks < 4; ks++) {
    size_t aoff0 = (size_t)(n0 + l16) * MM + ks * 32 + quad * 8;
    bf16x8 a0h = *(const bf16x8*)(v1phi + aoff0);
    bf16x8 a0l = *(const bf16x8*)(v1plo + aoff0);
#pragma unroll
    for (int t = 0; t < 12; t++) {
      int j = t * 64 + h0 + l16;
      size_t boff = ((size_t)(b * 16 + ks * 4 + quad) * TC + j) * 8;
      bf16x8 bhv = *(const bf16x8*)(kvBhi + boff);
      bf16x8 blv = *(const bf16x8*)(kvBlo + boff);
      acc[t] = __builtin_amdgcn_mfma_f32_16x16x32_bf16(bhv, a0h, acc[t], 0, 0, 0);
      acc[t] = __builtin_amdgcn_mfma_f32_16x16x32_bf16(blv, a0h, acc[t], 0, 0, 0);
      acc[t] = __builtin_amdgcn_mfma_f32_16x16x32_bf16(bhv, a0l, acc[t], 0, 0, 0);
    }
  }
  int n = n0 + l16;
  float idn = invden[n];
#pragma unroll
  for (int r = 0; r < 4; r++) {
    int h = h0 + quad * 4 + r;
    float o[12];
#pragma unroll
    for (int t = 0; t < 12; t++) o[t] = acc[t][r] * idn;
    float* dst = out + ((size_t)(b * HH + h) * NN + n) * TT;
    *(float4*)(dst) = make_float4(o[0], o[1], o[2], o[3]);
    *(float4*)(dst + 4) = make_float4(o[4], o[5], o[6], o[7]);
    *(float4*)(dst + 8) = make_float4(o[8], o[9], o[10], o[11]);
  }
}

extern "C" void kernel_launch(void* const* d_in, const int* in_sizes, int n_in,
                              void* d_out, int out_size, void* d_ws, size_t ws_size,
                              hipStream_t stream) {
  const float* input = (const float*)d_in[0];
  const float* nv1   = (const float*)d_in[1];
  const float* nv2   = (const float*)d_in[2];
  const float* Wi    = (const float*)d_in[3];
  const float* bi    = (const float*)d_in[4];
  const float* Wo    = (const float*)d_in[5];
  const float* bo    = (const float*)d_in[6];
  const float* proj  = (const float*)d_in[7];
  float* out = (float*)d_out;
  float* v1p = out + V1OFF;
  float* v2p = out + V2OFF;
  // x hi/lo planes alias the out0 region exactly (50331648 shorts each)
  unsigned short* xhi = (unsigned short*)d_out;
  unsigned short* xlo = xhi + 50331648;

  char* wsb = (char*)d_ws;
  const size_t MB = 1 << 20;
  unsigned short* v2phiT = (unsigned short*)(wsb + 0 * MB);
  unsigned short* v2ploT = (unsigned short*)(wsb + 1 * MB);
  unsigned short* v1phi  = (unsigned short*)(wsb + 2 * MB);
  unsigned short* v1plo  = (unsigned short*)(wsb + 3 * MB);
  unsigned short* whi    = (unsigned short*)(wsb + 4 * MB);
  unsigned short* wlo    = (unsigned short*)(wsb + 4 * MB + 8192);
  float* colsum  = (float*)(wsb + 4 * MB + 16384);
  float* rowmax2 = (float*)(wsb + 4 * MB + 16384 + 512);
  float* stab2   = (float*)(wsb + 4 * MB + 16384 + 512 + 16384);
  float* invden  = (float*)(wsb + 5 * MB);
  unsigned short* kvBhi = (unsigned short*)(wsb + 6 * MB);
  unsigned short* kvBlo = (unsigned short*)(wsb + 10 * MB);
  float* kvpart = (float*)(wsb + 14 * MB);

  // adaptive k-split for kv partials based on available ws
  size_t partBytes = (size_t)BB * KVELEM * 4;
  size_t avail = (ws_size > 14 * MB) ? ws_size - 14 * MB : 0;
  int NS = (avail >= 16 * partBytes) ? 16 :
           (avail >= 8 * partBytes) ? 8 : (avail >= 4 * partBytes ? 4 : 2);

  hipMemsetAsync(colsum, 0, MM * sizeof(float), stream);
  k_wsplit<<<16, 256, 0, stream>>>(Wi, Wo, whi, wlo);
  k_feat<<<NN, 128, 0, stream>>>(nv1, nv2, proj, v1p, v2p, rowmax2, v1phi, v1plo);
  k_stab<<<1, 256, 0, stream>>>(rowmax2, stab2);
  k_v2p<<<64, 128, 0, stream>>>(v2p, stab2, colsum, v2phiT, v2ploT);
  k_den<<<16, 256, 0, stream>>>(v1p, colsum, invden);
  k_point<<<dim3(64, 16, 3), 256, 0, stream>>>(input, whi, wlo, bi, bo, xhi, xlo);
  k_kv<<<dim3(6, NS, 16), 256, 0, stream>>>(xhi, xlo, v2phiT, v2ploT, kvpart);
  k_kvred<<<768, 256, 0, stream>>>(kvpart, kvBhi, kvBlo, NS);
  k_num<<<dim3(256, 16), 256, 0, stream>>>(v1phi, v1plo, kvBhi, kvBlo, invden, out);
}

// Round 11
// 616.656 us; speedup vs baseline: 1.1704x; 1.0653x over previous
//
#include <hip/hip_runtime.h>

#define BB 16
#define CIN 32
#define NN 4096
#define TT 12
#define HH 64
#define MM 128
#define DD 64
#define TC (TT*HH)            // 768
#define V1OFF 50331648        // B*H*N*T floats
#define V2OFF 50855936
#define KVELEM (MM*TC)        // 98304 per batch
#define NORMR 0.35355339059327373f   // 64^-0.25
#define RATIO 0.08838834764831845f   // 128^-0.5
#define FEPS 1e-4f

typedef __attribute__((ext_vector_type(8))) short bf16x8;
typedef __attribute__((ext_vector_type(4))) float f32x4;

union BF8 { unsigned short s[8]; bf16x8 v; };

__device__ inline float wave_max(float v) {
#pragma unroll
  for (int off = 32; off > 0; off >>= 1) v = fmaxf(v, __shfl_xor(v, off));
  return v;
}

__device__ inline unsigned short f2bf(float f) {
  unsigned int u = __float_as_uint(f);
  unsigned int r = (u + 0x7FFFu + ((u >> 16) & 1u)) >> 16;
  return (unsigned short)r;
}

// split float into hi/lo bf16 (hi + lo reconstructs to ~2^-17 rel)
__device__ inline void hilo(float v, unsigned short& h, unsigned short& l) {
  h = f2bf(v);
  float fh = __uint_as_float((unsigned int)h << 16);
  l = f2bf(v - fh);
}

// ---- tiny setup kernels -------------------------------------------------

// stack [Wi;Wo] into 128x32 and split hi/lo
__global__ __launch_bounds__(256) void k_wsplit(const float* __restrict__ Wi,
    const float* __restrict__ Wo, unsigned short* __restrict__ whi,
    unsigned short* __restrict__ wlo) {
  int idx = blockIdx.x * 256 + threadIdx.x;   // 4096
  int o = idx >> 5, c = idx & 31;
  float w = (o < 64) ? Wi[o * 32 + c] : Wo[(o - 64) * 32 + c];
  unsigned short h, l; hilo(w, h, l);
  whi[idx] = h; wlo[idx] = l;
}

// K1: per-row features. v1p final (+hi/lo planes); t2 = dash2-diag2 into v2p slot.
__global__ __launch_bounds__(128) void k_feat(const float* __restrict__ nv1,
    const float* __restrict__ nv2, const float* __restrict__ proj,
    float* __restrict__ v1p, float* __restrict__ t2, float* __restrict__ rowmax2,
    unsigned short* __restrict__ v1phi, unsigned short* __restrict__ v1plo) {
  int n = blockIdx.x, m = threadIdx.x;
  __shared__ float a1[DD], a2[DD], r1[2], r2[2];
  if (m < DD) a1[m] = nv1[n * DD + m];
  else        a2[m - DD] = nv2[n * DD + (m - DD)];
  __syncthreads();
  float s1 = 0.f, s2 = 0.f, d1 = 0.f, d2 = 0.f;
  const float* pr = proj + m * DD;
#pragma unroll 8
  for (int d = 0; d < DD; d++) {
    float x1 = a1[d], x2 = a2[d], p = pr[d];
    s1 += x1 * x1; s2 += x2 * x2;
    d1 += x1 * p;  d2 += x2 * p;
  }
  d1 *= NORMR; d2 *= NORMR;
  float diag1 = 0.0625f * s1, diag2 = 0.0625f * s2;
  float mx1 = wave_max(d1), mx2 = wave_max(d2);
  int wv = m >> 6;
  if ((m & 63) == 0) { r1[wv] = mx1; r2[wv] = mx2; }
  __syncthreads();
  mx1 = fmaxf(r1[0], r1[1]); mx2 = fmaxf(r2[0], r2[1]);
  float val = RATIO * (__expf(d1 - diag1 - mx1) + FEPS);
  v1p[n * MM + m] = val;
  unsigned short h, l; hilo(val, h, l);
  v1phi[n * MM + m] = h;
  v1plo[n * MM + m] = l;
  t2[n * MM + m] = d2 - diag2;
  if (m == 0) rowmax2[n] = mx2;
}

// K2: global max of dash2
__global__ __launch_bounds__(256) void k_stab(const float* __restrict__ rowmax2,
                                              float* __restrict__ stab2) {
  int tid = threadIdx.x;
  float mx = -3.4e38f;
  for (int i = tid; i < NN; i += 256) mx = fmaxf(mx, rowmax2[i]);
  mx = wave_max(mx);
  __shared__ float r[4];
  if ((tid & 63) == 0) r[tid >> 6] = mx;
  __syncthreads();
  if (tid == 0) stab2[0] = fmaxf(fmaxf(r[0], r[1]), fmaxf(r[2], r[3]));
}

// K3: finish v2p in place, colsum, and write MFMA-FRAGMENT-PACKED hi/lo
// planes: pack[((n>>5)*4 + ((n>>3)&3))*1024 + m*8 + (n&7)]. This makes
// k_kv's A-loads 256B-contiguous per quarter-wave (was [m][n] layout:
// 16 lanes at 8KB stride = 16 lines per load instruction). Block-disjoint
// 8KB chunk regions per 64-n block — 64B-line rule satisfied.
__global__ __launch_bounds__(128) void k_v2p(float* __restrict__ t2v2p,
    const float* __restrict__ stab2, float* __restrict__ colsum,
    unsigned short* __restrict__ v2pkhi, unsigned short* __restrict__ v2pklo) {
  int m = threadIdx.x;
  float stab = stab2[0];
  float cs = 0.f;
  int n0 = blockIdx.x * 64;
  for (int i = 0; i < 64; i++) {
    int n = n0 + i;
    float v = RATIO * (__expf(t2v2p[n * MM + m] - stab) + FEPS);
    t2v2p[n * MM + m] = v;
    cs += v;
    unsigned short h, l; hilo(v, h, l);
    int off = ((n >> 5) * 4 + ((n >> 3) & 3)) * (MM * 8) + m * 8 + (n & 7);
    v2pkhi[off] = h;
    v2pklo[off] = l;
  }
  atomicAdd(&colsum[m], cs);
}

// K4: inv_den[n] = 1 / (v1p[n,:] . colsum)
__global__ __launch_bounds__(256) void k_den(const float* __restrict__ v1p,
    const float* __restrict__ colsum, float* __restrict__ invden) {
  __shared__ float cs[MM];
  int tid = threadIdx.x;
  if (tid < MM) cs[tid] = colsum[tid];
  __syncthreads();
  int n = blockIdx.x * 256 + tid;
  const float* vp = v1p + (size_t)n * MM;
  float s = 0.f;
#pragma unroll 8
  for (int m = 0; m < MM; m++) s += vp[m] * cs[m];
  invden[n] = 1.0f / s;
}

// ---- K5: conv+gate via MFMA. A = stacked W[128x32] hi/lo (regs), B = input.
// x stored hi/lo bf16 planes, layout [b][n/8][j=t*64+h][n%8].
// t-split 3-way (4 t per block); stream-once reads; 4KB-aligned disjoint
// write chunks per block (64B-line rule).
__global__ __launch_bounds__(256) void k_point(const float* __restrict__ inp,
    const unsigned short* __restrict__ whi, const unsigned short* __restrict__ wlo,
    const float* __restrict__ bi, const float* __restrict__ bo,
    unsigned short* __restrict__ xhi, unsigned short* __restrict__ xlo) {
  int tid = threadIdx.x;
  int wv = tid >> 6, lane = tid & 63;
  int quad = lane >> 4, l16 = lane & 15;
  int b = blockIdx.y;
  int t0 = blockIdx.z * 4;              // {0,4,8}: float4 at +t0 stays 16B-aligned
  int n = blockIdx.x * 64 + wv * 16 + l16;

  bf16x8 wh[8], wl[8];
#pragma unroll
  for (int tile = 0; tile < 8; tile++) {
    int m = tile * 16 + l16;
    wh[tile] = *(const bf16x8*)(whi + m * 32 + quad * 8);
    wl[tile] = *(const bf16x8*)(wlo + m * 32 + quad * 8);
  }
  f32x4 binit[8];
#pragma unroll
  for (int tile = 0; tile < 8; tile++) {
    const float* bp = (tile < 4) ? bi : bo;
#pragma unroll
    for (int r = 0; r < 4; r++)
      binit[tile][r] = bp[(tile & 3) * 16 + quad * 4 + r];
  }
  const float* ipb = inp + ((size_t)b * CIN + quad * 8) * (NN * TT) + (size_t)n * TT + t0;

  // preload this block's 4 t for the 8 channels of this quad; convert once.
  BF8 xh[4], xl[4];
#pragma unroll
  for (int j = 0; j < 8; j++) {
    float4 r0 = *(const float4*)(ipb + (size_t)j * (NN * TT));
    float row[4] = {r0.x, r0.y, r0.z, r0.w};
#pragma unroll
    for (int tt = 0; tt < 4; tt++) {
      unsigned short h, l; hilo(row[tt], h, l);
      xh[tt].s[j] = h; xl[tt].s[j] = l;
    }
  }

  size_t xbase = ((size_t)(b * (NN / 8) + (n >> 3)) * TC) * 8 + (n & 7);
#pragma unroll
  for (int tt = 0; tt < 4; tt++) {
    int t = t0 + tt;
    f32x4 acc[8];
#pragma unroll
    for (int tile = 0; tile < 8; tile++) acc[tile] = binit[tile];
#pragma unroll
    for (int tile = 0; tile < 8; tile++) {
      acc[tile] = __builtin_amdgcn_mfma_f32_16x16x32_bf16(wh[tile], xh[tt].v, acc[tile], 0, 0, 0);
      acc[tile] = __builtin_amdgcn_mfma_f32_16x16x32_bf16(wh[tile], xl[tt].v, acc[tile], 0, 0, 0);
      acc[tile] = __builtin_amdgcn_mfma_f32_16x16x32_bf16(wl[tile], xh[tt].v, acc[tile], 0, 0, 0);
    }
#pragma unroll
    for (int i = 0; i < 4; i++) {
#pragma unroll
      for (int r = 0; r < 4; r++) {
        float h1 = acc[i][r], h2 = acc[i + 4][r];
        float g = h2 / (1.f + __expf(-h1));
        unsigned short gh, gl; hilo(g, gh, gl);
        int j = t * 64 + i * 16 + quad * 4 + r;
        xhi[xbase + (size_t)j * 8] = gh;
        xlo[xbase + (size_t)j * 8] = gl;
      }
    }
  }
}

// ---- K6: kv partials via MFMA. A = packed v2p hi/lo, B = x hi/lo.
// grid (6 jt, NS, 16 b); wave handles all 8 m-tiles x 32 j (2 j-frags).
// A-loads now hit the fragment-packed layout: 8 contiguous shorts per
// lane, 256B contiguous per quarter-wave (same pattern as B). Was the
// [m][n] layout: 16 lanes x 8KB stride = 16 lines per load — the
// latency bottleneck at 137us / 1.6TB/s / all-pipes-11%.
__global__ __launch_bounds__(256) void k_kv(const unsigned short* __restrict__ xhi,
    const unsigned short* __restrict__ xlo,
    const unsigned short* __restrict__ v2pkhi, const unsigned short* __restrict__ v2pklo,
    float* __restrict__ kvpart) {
  int tid = threadIdx.x, wv = tid >> 6, lane = tid & 63;
  int quad = lane >> 4, l16 = lane & 15;
  int jt = blockIdx.x, nsI = blockIdx.y, b = blockIdx.z;
  int NS = gridDim.y, kPer = NN / NS;
  int j0 = jt * 128 + wv * 32;
  f32x4 zz = {0.f, 0.f, 0.f, 0.f};
  f32x4 acc[8][2];
#pragma unroll
  for (int t = 0; t < 8; t++) { acc[t][0] = zz; acc[t][1] = zz; }
  int kend = nsI * kPer + kPer;
  for (int k0 = nsI * kPer; k0 < kend; k0 += 32) {
    size_t abase = ((size_t)(k0 >> 5) * 4 + quad) * (MM * 8);
    bf16x8 ah[8], al[8];
#pragma unroll
    for (int tile = 0; tile < 8; tile++) {
      size_t off = abase + (size_t)(tile * 16 + l16) * 8;
      ah[tile] = *(const bf16x8*)(v2pkhi + off);
      al[tile] = *(const bf16x8*)(v2pklo + off);
    }
    bf16x8 bh[2], bl[2];
#pragma unroll
    for (int jf = 0; jf < 2; jf++) {
      size_t off = ((size_t)(b * (NN / 8) + (k0 >> 3) + quad) * TC + j0 + jf * 16 + l16) * 8;
      bh[jf] = *(const bf16x8*)(xhi + off);
      bl[jf] = *(const bf16x8*)(xlo + off);
    }
#pragma unroll
    for (int tile = 0; tile < 8; tile++) {
#pragma unroll
      for (int jf = 0; jf < 2; jf++) {
        acc[tile][jf] = __builtin_amdgcn_mfma_f32_16x16x32_bf16(ah[tile], bh[jf], acc[tile][jf], 0, 0, 0);
        acc[tile][jf] = __builtin_amdgcn_mfma_f32_16x16x32_bf16(ah[tile], bl[jf], acc[tile][jf], 0, 0, 0);
        acc[tile][jf] = __builtin_amdgcn_mfma_f32_16x16x32_bf16(al[tile], bh[jf], acc[tile][jf], 0, 0, 0);
      }
    }
  }
  float* dst = kvpart + (size_t)(nsI * BB + b) * KVELEM;
#pragma unroll
  for (int tile = 0; tile < 8; tile++)
#pragma unroll
    for (int jf = 0; jf < 2; jf++)
#pragma unroll
      for (int r = 0; r < 4; r++)
        dst[(size_t)(tile * 16 + quad * 4 + r) * TC + j0 + jf * 16 + l16] = acc[tile][jf][r];
}

// K6b: reduce NS partials, emit kvB hi/lo planes [b][m/8][j][m%8]
__global__ __launch_bounds__(256) void k_kvred(const float* __restrict__ kvpart,
    unsigned short* __restrict__ kvBhi, unsigned short* __restrict__ kvBlo, int NS) {
  int gid = blockIdx.x * 256 + threadIdx.x;   // 196608
  int j = gid % TC; int rest = gid / TC; int mgrp = rest & 15; int b = rest >> 4;
  float s[8];
#pragma unroll
  for (int mi = 0; mi < 8; mi++) s[mi] = 0.f;
  for (int ns = 0; ns < NS; ns++) {
    const float* p = kvpart + ((size_t)(ns * BB + b) * MM + mgrp * 8) * TC + j;
#pragma unroll
    for (int mi = 0; mi < 8; mi++) s[mi] += p[(size_t)mi * TC];
  }
  unsigned short hs[8] __attribute__((aligned(16)));
  unsigned short ls[8] __attribute__((aligned(16)));
#pragma unroll
  for (int mi = 0; mi < 8; mi++) hilo(s[mi], hs[mi], ls[mi]);
  size_t off = ((size_t)(b * 16 + mgrp) * TC + j) * 8;
  *(uint4*)(kvBhi + off) = *(const uint4*)hs;
  *(uint4*)(kvBlo + off) = *(const uint4*)ls;
}

// ---- K7: num = v1p . kv via MFMA, scale by invden, write [B,H,N,T].
// grid (256 nt, 16 b); wave: 16 n x 16 h x all 12 t.
// SWAPPED-OPERAND MFMA: mfma(kvB_frag, v1p_frag) — D transposed so 16
// lanes cover 16 consecutive n (768B contiguous per quarter-wave).
__global__ __launch_bounds__(256) void k_num(const unsigned short* __restrict__ v1phi,
    const unsigned short* __restrict__ v1plo, const unsigned short* __restrict__ kvBhi,
    const unsigned short* __restrict__ kvBlo, const float* __restrict__ invden,
    float* __restrict__ out) {
  int tid = threadIdx.x, wv = tid >> 6, lane = tid & 63;
  int quad = lane >> 4, l16 = lane & 15;
  int nt = blockIdx.x, b = blockIdx.y;
  int n0 = nt * 16;
  int h0 = wv * 16;
  f32x4 zz = {0.f, 0.f, 0.f, 0.f};
  f32x4 acc[12];
#pragma unroll
  for (int t = 0; t < 12; t++) acc[t] = zz;
#pragma unroll
  for (int ks = 0; ks < 4; ks++) {
    size_t aoff0 = (size_t)(n0 + l16) * MM + ks * 32 + quad * 8;
    bf16x8 a0h = *(const bf16x8*)(v1phi + aoff0);
    bf16x8 a0l = *(const bf16x8*)(v1plo + aoff0);
#pragma unroll
    for (int t = 0; t < 12; t++) {
      int j = t * 64 + h0 + l16;
      size_t boff = ((size_t)(b * 16 + ks * 4 + quad) * TC + j) * 8;
      bf16x8 bhv = *(const bf16x8*)(kvBhi + boff);
      bf16x8 blv = *(const bf16x8*)(kvBlo + boff);
      acc[t] = __builtin_amdgcn_mfma_f32_16x16x32_bf16(bhv, a0h, acc[t], 0, 0, 0);
      acc[t] = __builtin_amdgcn_mfma_f32_16x16x32_bf16(blv, a0h, acc[t], 0, 0, 0);
      acc[t] = __builtin_amdgcn_mfma_f32_16x16x32_bf16(bhv, a0l, acc[t], 0, 0, 0);
    }
  }
  int n = n0 + l16;
  float idn = invden[n];
#pragma unroll
  for (int r = 0; r < 4; r++) {
    int h = h0 + quad * 4 + r;
    float o[12];
#pragma unroll
    for (int t = 0; t < 12; t++) o[t] = acc[t][r] * idn;
    float* dst = out + ((size_t)(b * HH + h) * NN + n) * TT;
    *(float4*)(dst) = make_float4(o[0], o[1], o[2], o[3]);
    *(float4*)(dst + 4) = make_float4(o[4], o[5], o[6], o[7]);
    *(float4*)(dst + 8) = make_float4(o[8], o[9], o[10], o[11]);
  }
}

extern "C" void kernel_launch(void* const* d_in, const int* in_sizes, int n_in,
                              void* d_out, int out_size, void* d_ws, size_t ws_size,
                              hipStream_t stream) {
  const float* input = (const float*)d_in[0];
  const float* nv1   = (const float*)d_in[1];
  const float* nv2   = (const float*)d_in[2];
  const float* Wi    = (const float*)d_in[3];
  const float* bi    = (const float*)d_in[4];
  const float* Wo    = (const float*)d_in[5];
  const float* bo    = (const float*)d_in[6];
  const float* proj  = (const float*)d_in[7];
  float* out = (float*)d_out;
  float* v1p = out + V1OFF;
  float* v2p = out + V2OFF;
  // x hi/lo planes alias the out0 region exactly (50331648 shorts each)
  unsigned short* xhi = (unsigned short*)d_out;
  unsigned short* xlo = xhi + 50331648;

  char* wsb = (char*)d_ws;
  const size_t MB = 1 << 20;
  unsigned short* v2pkhi = (unsigned short*)(wsb + 0 * MB);
  unsigned short* v2pklo = (unsigned short*)(wsb + 1 * MB);
  unsigned short* v1phi  = (unsigned short*)(wsb + 2 * MB);
  unsigned short* v1plo  = (unsigned short*)(wsb + 3 * MB);
  unsigned short* whi    = (unsigned short*)(wsb + 4 * MB);
  unsigned short* wlo    = (unsigned short*)(wsb + 4 * MB + 8192);
  float* colsum  = (float*)(wsb + 4 * MB + 16384);
  float* rowmax2 = (float*)(wsb + 4 * MB + 16384 + 512);
  float* stab2   = (float*)(wsb + 4 * MB + 16384 + 512 + 16384);
  float* invden  = (float*)(wsb + 5 * MB);
  unsigned short* kvBhi = (unsigned short*)(wsb + 6 * MB);
  unsigned short* kvBlo = (unsigned short*)(wsb + 10 * MB);
  float* kvpart = (float*)(wsb + 14 * MB);

  // adaptive k-split for kv partials based on available ws
  size_t partBytes = (size_t)BB * KVELEM * 4;
  size_t avail = (ws_size > 14 * MB) ? ws_size - 14 * MB : 0;
  int NS = (avail >= 16 * partBytes) ? 16 :
           (avail >= 8 * partBytes) ? 8 : (avail >= 4 * partBytes ? 4 : 2);

  hipMemsetAsync(colsum, 0, MM * sizeof(float), stream);
  k_wsplit<<<16, 256, 0, stream>>>(Wi, Wo, whi, wlo);
  k_feat<<<NN, 128, 0, stream>>>(nv1, nv2, proj, v1p, v2p, rowmax2, v1phi, v1plo);
  k_stab<<<1, 256, 0, stream>>>(rowmax2, stab2);
  k_v2p<<<64, 128, 0, stream>>>(v2p, stab2, colsum, v2pkhi, v2pklo);
  k_den<<<16, 256, 0, stream>>>(v1p, colsum, invden);
  k_point<<<dim3(64, 16, 3), 256, 0, stream>>>(input, whi, wlo, bi, bo, xhi, xlo);
  k_kv<<<dim3(6, NS, 16), 256, 0, stream>>>(xhi, xlo, v2pkhi, v2pklo, kvpart);
  k_kvred<<<768, 256, 0, stream>>>(kvpart, kvBhi, kvBlo, NS);
  k_num<<<dim3(256, 16), 256, 0, stream>>>(v1phi, v1plo, kvBhi, kvBlo, invden, out);
}